// Round 7
// baseline (3430.603 us; speedup 1.0000x reference)
//
#include <hip/hip_runtime.h>

// PointNet++ SetAbstraction: FPS -> ball query -> grouped MLP(67->64->64->128, BN+ReLU) -> maxpool
// B=8, N=8192, S=2048, K=32, F=64.
//
// d_out: [8][2048][3] center_xyzs then [8][2048][128] center_feats (fp32).
// d_ws: 16576 floats transposed weights + u32 ring[8][2048] (64KB) index
//       mailboxes. Total ws use = 131,840 B.
//
// EXACTNESS INVARIANTS (validated R4..R21: absmax 7.8e-3 < 5.4e-2):
//   - discrete-decision math contraction-free (contract(off) helpers).
//   - np.sum last-axis n=3: FORWARD plain adds (x0+x1)+x2  [FPS dist, |c|^2, |x|^2]
//   - einsum dot: ascending FMA chain fma(c2,x2, fma(c1,x1, c0*x0))  [ball query]
//   - FPS argmax: u64 key (float_bits(bv)<<13)|(8191-idx); TOTAL order.
//   - v2f ops round per-half identically to scalar (R9/R10-validated).
//   - MLP accumulation order ascending-c preserved across layout changes.
//   - R20: consumers read centers from xyzs[b][i0] — bit-identical to mirror.
//   - R21: quad-max argmax (per-quad fmax tree + quad chain + post-chain
//     reconstruction) == old 32-link chain bit-for-bit (validated R6 PASS).
//   - R22 (this round): chain pairing changes WHERE each batch's chain runs,
//     not its math — per-chain code is the R21 body verbatim; FPS winner
//     coords now read from global xyzs[3*i0] = same bits as the old LDS
//     mirror sX[i0] (mirror was a copy of exactly these values).
//
// PERF LESSONS (measured):
//   R5: dynamically-indexed per-thread arrays get LDS-demoted — named/unrolled only.
//   R6/R7: __shfl_* lowers to ds_permute (LDS pipe) — use DPP for reductions.
//   R8..R11: FPS 256thr/1-wave-per-SIMD best; barrier cost scales with waves.
//   R13/R14: FPS dist-loop source form: v2f-source fastest (beat pk-inline-asm
//       1832 vs 1902). KEEP fps_sqdist_v2 + fminf update order EXACTLY as-is.
//   R13: sa o-split 2 waves WIN. R14: +LDS b128 (stride 68, 4-c chunks).
//   R16: producer-consumer fusion works structurally (mega dur tracks FPS).
//   R17: co-residency interference REFUTED; setprio(3) suffices.
//   R18: vmem stores inside the FPS loop pay their ack latency at the next
//       s_barrier (hipcc drains vmcnt(0) before every barrier) — batch them.
//   R19: handoff needs formal ordering + slack, OR no ordering requirement.
//   R20: relaxed 4B self-validating mailboxes (simplest correct protocol).
//   R21: FPS iter is latency-bound: ~790cyc VALU issue vs ~2150cyc measured.
//       Chain 32->8 links won 105us. Serial tail (DPP chain + barrier + LDS
//       exchange + winner broadcast) ~1300cyc exposed at 1 wave/SIMD.
//   R22 (this round): TWO independent FPS chains (batches 2b,2b+1) per block,
//       one shared barrier/iter; compiler statically interleaves chain-A's
//       latency gaps with chain-B's distance instrs. 4 FPS blocks. Coord
//       mirror dropped (2x96KB > LDS): LOADQ from global (R1-validated) and
//       winner coords from L2 (~200cyc, cross-chain overlapped). LDS 35KB.
//       VGPR ~300 (coords 2x96 + minds 2x32) — under 450 no-spill threshold.

#define NPTS 8192
#define SCTR 2048
#define NB   8
#define NFPS 4                                // FPS blocks (2 batches each)
#define KNN  32
#define NF   64
#define WT_FLOATS (67*64 + 64*64 + 64*128)   // 16576
#define RING_U32  (NB * SCTR)                 // 16384

typedef float v2f __attribute__((ext_vector_type(2)));

// d = (dx*dx + dy*dy) + dz*dz for TWO points, exact fp32 mul/add order,
// NO contraction. KEEP THIS SOURCE FORM (R13/R14: fastest measured variant).
__device__ __forceinline__ v2f fps_sqdist_v2(v2f px, v2f py, v2f pz,
                                             v2f lx, v2f ly, v2f lz) {
#pragma clang fp contract(off)
  v2f dx = px - lx;
  v2f dy = py - ly;
  v2f dz = pz - lz;
  v2f xx = dx * dx;
  v2f yy = dy * dy;
  v2f zz = dz * dz;
  return (xx + yy) + zz;
}

// (x*x + y*y) + z*z, NO contraction (np.sum forward order, n=3).
__device__ __forceinline__ float sumsq3(float x, float y, float z) {
#pragma clang fp contract(off)
  return (x * x + y * y) + z * z;
}

// Ball-query expanded form: (sc + sx) - 2*dot, NO contraction on the adds.
__device__ __forceinline__ float bq_d2(float sc, float sx,
                                       float cx, float cy, float cz,
                                       float x, float y, float z) {
#pragma clang fp contract(off)
  float dt = fmaf(cz, z, fmaf(cy, y, cx * x));
  return (sc + sx) - 2.0f * dt;
}

// u64 max with the partner lane's key fetched via DPP (VALU pipe, no LDS).
template <int CTRL>
__device__ __forceinline__ unsigned long long kmax_dpp(unsigned long long k) {
  int lo = (int)(unsigned int)(k & 0xFFFFFFFFull);
  int hi = (int)(unsigned int)(k >> 32);
  int slo = __builtin_amdgcn_update_dpp(lo, lo, CTRL, 0xF, 0xF, false);
  int shi = __builtin_amdgcn_update_dpp(hi, hi, CTRL, 0xF, 0xF, false);
  unsigned long long sk =
      ((unsigned long long)(unsigned int)shi << 32) | (unsigned int)slo;
  return sk > k ? sk : k;
}

// ---------------------------------------------------------------------------
// Kernel 0: weight transpose + ring reset (stream-ordered; re-zeroes the ring
// on every graph replay BEFORE the mega kernel runs).
// ---------------------------------------------------------------------------
__global__ __launch_bounds__(256) void init_kernel(
    const float* __restrict__ w1, const float* __restrict__ w2,
    const float* __restrict__ w3, float* __restrict__ wT,
    unsigned* __restrict__ ring)
{
  const int t = threadIdx.x;
  int idx = blockIdx.x * 256 + t;
  if (idx < RING_U32) ring[idx] = 0u;   // bit31 clear = empty
  if (idx < 67*64) {
    int c = idx >> 6, o = idx & 63;
    wT[idx] = w1[o*67 + c];
  } else if (idx < 67*64 + 64*64) {
    int r = idx - 67*64; int c = r >> 6, o = r & 63;
    wT[idx] = w2[o*64 + c];
  } else if (idx < 67*64 + 64*64 + 64*128) {
    int r = idx - (67*64 + 64*64); int c = r >> 7, o = r & 127;
    wT[idx] = w3[o*64 + c];
  }
}

// ---------------------------------------------------------------------------
// Mega kernel. Blocks 0..3: FPS producers, TWO chains each (batches 2b,2b+1).
// Blocks 4..8195: one-shot sa consumers, two 128-thread halves per block,
// cid = 2*(blk-4)+half, s-major interleave (b=cid&7, s=cid>>3).
// Shared LDS (8784 floats = 35,136 B):
//   FPS: hist0(int)[0..2047] hist1(int)[2048..4095] redk(u64[2][2][4])[4096..4127]
//   SA : in_/y_ half0 [0..4351], half1 [4352..8703]; gidx [8704..8767];
//        csl [8768..8775]
// ---------------------------------------------------------------------------
__global__ __launch_bounds__(256, 1) void mega_kernel(
    const float* __restrict__ xyzs, const float* __restrict__ feats,
    float* centers, const float* __restrict__ wT, unsigned* ring,
    const float* __restrict__ b1, const float* __restrict__ g1, const float* __restrict__ bt1,
    const float* __restrict__ m1, const float* __restrict__ v1,
    const float* __restrict__ b2, const float* __restrict__ g2, const float* __restrict__ bt2,
    const float* __restrict__ m2, const float* __restrict__ v2,
    const float* __restrict__ b3, const float* __restrict__ g3, const float* __restrict__ bt3,
    const float* __restrict__ m3, const float* __restrict__ v3,
    float* out_feats)
{
  __shared__ __align__(16) float smem[8784];

  if (blockIdx.x < NFPS) {
    // ========================= FPS (two chains) ==========================
    __builtin_amdgcn_s_setprio(3);
    const int bi = blockIdx.x;
    const int t = threadIdx.x;
    const int t4 = 4 * t;
    const float* xb0 = xyzs + (size_t)(2*bi)     * NPTS * 3;
    const float* xb1 = xyzs + (size_t)(2*bi + 1) * NPTS * 3;
    unsigned* ring0 = ring + (2*bi)     * SCTR;
    unsigned* ring1 = ring + (2*bi + 1) * SCTR;
    float* cb0 = centers + (size_t)(2*bi)     * SCTR * 3;
    float* cb1 = centers + (size_t)(2*bi + 1) * SCTR * 3;
    int* hist0 = (int*)smem;             // [2048]
    int* hist1 = (int*)smem + 2048;      // [2048]
    unsigned long long* redk = (unsigned long long*)(smem + 4096);  // [ch][pb][4]

    // 32 loop-invariant points PER CHAIN (8 quads strided 1024) in NAMED
    // registers, loaded from global (AoS 48B/thread/quad, R1-validated).
#define LOADQ(QX, QY, QZ, XB, QOFF)                                           \
    { const float4* p_ = (const float4*)((XB) + (size_t)3 * ((QOFF) + t4));   \
      float4 l0 = p_[0], l1 = p_[1], l2 = p_[2];                              \
      QX = make_float4(l0.x, l0.w, l1.z, l2.y);                               \
      QY = make_float4(l0.y, l1.x, l1.w, l2.z);                               \
      QZ = make_float4(l0.z, l1.y, l2.x, l2.w); }

    float4 xA0,yA0,zA0,xB0,yB0,zB0,xC0,yC0,zC0,xD0,yD0,zD0;
    float4 xE0,yE0,zE0,xF0,yF0,zF0,xG0,yG0,zG0,xH0,yH0,zH0;
    float4 xA1,yA1,zA1,xB1,yB1,zB1,xC1,yC1,zC1,xD1,yD1,zD1;
    float4 xE1,yE1,zE1,xF1,yF1,zF1,xG1,yG1,zG1,xH1,yH1,zH1;
    LOADQ(xA0,yA0,zA0, xb0, 0);    LOADQ(xB0,yB0,zB0, xb0, 1024);
    LOADQ(xC0,yC0,zC0, xb0, 2048); LOADQ(xD0,yD0,zD0, xb0, 3072);
    LOADQ(xE0,yE0,zE0, xb0, 4096); LOADQ(xF0,yF0,zF0, xb0, 5120);
    LOADQ(xG0,yG0,zG0, xb0, 6144); LOADQ(xH0,yH0,zH0, xb0, 7168);
    LOADQ(xA1,yA1,zA1, xb1, 0);    LOADQ(xB1,yB1,zB1, xb1, 1024);
    LOADQ(xC1,yC1,zC1, xb1, 2048); LOADQ(xD1,yD1,zD1, xb1, 3072);
    LOADQ(xE1,yE1,zE1, xb1, 4096); LOADQ(xF1,yF1,zF1, xb1, 5120);
    LOADQ(xG1,yG1,zG1, xb1, 6144); LOADQ(xH1,yH1,zH1, xb1, 7168);
#undef LOADQ

    float4 mA0 = make_float4(1e10f,1e10f,1e10f,1e10f);
    float4 mB0=mA0,mC0=mA0,mD0=mA0,mE0=mA0,mF0=mA0,mG0=mA0,mH0=mA0;
    float4 mA1=mA0,mB1=mA0,mC1=mA0,mD1=mA0,mE1=mA0,mF1=mA0,mG1=mA0,mH1=mA0;

    if (t == 0) { hist0[0] = 0; hist1[0] = 0; }   // first center = index 0
    float lx0 = xb0[0], ly0 = xb0[1], lz0 = xb0[2];
    float lx1 = xb1[0], ly1 = xb1[1], lz1 = xb1[2];
    int stash0 = 0, stash1 = 0;

// R21 quad-max body (verbatim math): min-updates + per-quad fmax tree +
// quad chain link (strict >). Distance source form UNCHANGED.
#define FPS_QUAD(QX, QY, QZ, MV, QID, BV, BQ)                                   \
  do {                                                                          \
    v2f d;                                                                      \
    d = fps_sqdist_v2((v2f){QX.x,QX.y}, (v2f){QY.x,QY.y}, (v2f){QZ.x,QZ.y},     \
                      lxv, lyv, lzv);                                           \
    MV.x = fminf(MV.x, d.x);                                                    \
    MV.y = fminf(MV.y, d.y);                                                    \
    d = fps_sqdist_v2((v2f){QX.z,QX.w}, (v2f){QY.z,QY.w}, (v2f){QZ.z,QZ.w},     \
                      lxv, lyv, lzv);                                           \
    MV.z = fminf(MV.z, d.x);                                                    \
    MV.w = fminf(MV.w, d.y);                                                    \
    float qm_ = fmaxf(fmaxf(MV.x, MV.y), fmaxf(MV.z, MV.w));                    \
    if (qm_ > BV) { BV = qm_; BQ = (QID); }                                     \
  } while (0)

// One chain's local step: dist block -> dual quad chains -> reconstruction ->
// u64 key -> 6-step DPP wave reduction -> lane63 writes redk[CH][pb][wave].
#define CHAIN_LOCAL(SUF, CH, LX, LY, LZ)                                        \
    {                                                                           \
      float bv0 = -1.0f, bv1 = -1.0f; int bq0 = 0, bq1 = 4;                     \
      {                                                                         \
        v2f lxv = {LX, LX}, lyv = {LY, LY}, lzv = {LZ, LZ};                     \
        FPS_QUAD(xA##SUF, yA##SUF, zA##SUF, mA##SUF, 0, bv0, bq0);              \
        FPS_QUAD(xB##SUF, yB##SUF, zB##SUF, mB##SUF, 1, bv0, bq0);              \
        FPS_QUAD(xC##SUF, yC##SUF, zC##SUF, mC##SUF, 2, bv0, bq0);              \
        FPS_QUAD(xD##SUF, yD##SUF, zD##SUF, mD##SUF, 3, bv0, bq0);              \
        FPS_QUAD(xE##SUF, yE##SUF, zE##SUF, mE##SUF, 4, bv1, bq1);              \
        FPS_QUAD(xF##SUF, yF##SUF, zF##SUF, mF##SUF, 5, bv1, bq1);              \
        FPS_QUAD(xG##SUF, yG##SUF, zG##SUF, mG##SUF, 6, bv1, bq1);              \
        FPS_QUAD(xH##SUF, yH##SUF, zH##SUF, mH##SUF, 7, bv1, bq1);              \
      }                                                                         \
      float bv = bv0; int bq = bq0;                                             \
      if (bv1 > bv0) { bv = bv1; bq = bq1; }                                    \
      float4 s0_ = (bq & 1) ? mB##SUF : mA##SUF;                                \
      float4 s1_ = (bq & 1) ? mD##SUF : mC##SUF;                                \
      float4 s2_ = (bq & 1) ? mF##SUF : mE##SUF;                                \
      float4 s3_ = (bq & 1) ? mH##SUF : mG##SUF;                                \
      float4 p0_ = (bq & 2) ? s1_ : s0_;                                        \
      float4 p1_ = (bq & 2) ? s3_ : s2_;                                        \
      float4 mq_ = (bq & 4) ? p1_ : p0_;                                        \
      int j_ = (bv == mq_.x) ? 0 : ((bv == mq_.y) ? 1 : ((bv == mq_.z) ? 2 : 3)); \
      int bg = (bq << 10) + t4 + j_;                                            \
      unsigned long long key =                                                  \
          ((unsigned long long)__float_as_uint(bv) << 13) |                     \
          (unsigned long long)(8191 - bg);                                      \
      key = kmax_dpp<0x111>(key);                                               \
      key = kmax_dpp<0x112>(key);                                               \
      key = kmax_dpp<0x114>(key);                                               \
      key = kmax_dpp<0x118>(key);                                               \
      key = kmax_dpp<0x142>(key);                                               \
      key = kmax_dpp<0x143>(key);                                               \
      if ((t & 63) == 63) redk[(CH)*8 + pb*4 + (t >> 6)] = key;                 \
    }

    for (int s = 1; s < SCTR; ++s) {
      const int pb = s & 1;          // ping-pong slot set (WAR across iters)
      CHAIN_LOCAL(0, 0, lx0, ly0, lz0)
      CHAIN_LOCAL(1, 1, lx1, ly1, lz1)
      __syncthreads();

      // cross-wave merge + winner-coord fetch, both chains (independent ->
      // compiler overlaps the two LDS reads / DPP merges / global loads).
      unsigned long long k40 = redk[pb*4 + (t & 3)];
      k40 = kmax_dpp<0xB1>(k40);     // quad_perm [1,0,3,2]
      k40 = kmax_dpp<0x4E>(k40);     // quad_perm [2,3,0,1]
      int i00 = 8191 - (int)(k40 & 0x1FFFull);
      unsigned long long k41 = redk[8 + pb*4 + (t & 3)];
      k41 = kmax_dpp<0xB1>(k41);
      k41 = kmax_dpp<0x4E>(k41);
      int i01 = 8191 - (int)(k41 & 0x1FFFull);

      const float* wp0 = xb0 + 3 * i00;   // L2-resident input: same bits as
      const float* wp1 = xb1 + 3 * i01;   // the old LDS mirror (R22)
      lx0 = wp0[0]; ly0 = wp0[1]; lz0 = wp0[2];
      lx1 = wp1[0]; ly1 = wp1[1]; lz1 = wp1[2];
      if (t == 0) { hist0[s] = i00; hist1[s] = i01; }

      // per-lane stashes; publish 16 mailboxes per chain every 16 iters
      // (RELAXED 4B self-validating messages — R20).
      if (t < 16 && (s & 15) == t) stash0 = i00;
      if (t >= 16 && t < 32 && (s & 15) == (t - 16)) stash1 = i01;
      if ((s & 15) == 15) {
        if (t < 16) {
          __hip_atomic_store(ring0 + (s - 15) + t,
                             0x80000000u | (unsigned)stash0,
                             __ATOMIC_RELAXED, __HIP_MEMORY_SCOPE_AGENT);
        } else if (t < 32) {
          __hip_atomic_store(ring1 + (s - 15) + (t - 16),
                             0x80000000u | (unsigned)stash1,
                             __ATOMIC_RELAXED, __HIP_MEMORY_SCOPE_AGENT);
        }
      }
    }
#undef CHAIN_LOCAL
#undef FPS_QUAD

    // epilogue: write centers to d_out (harness only — consumers use ring).
    __syncthreads();
    for (int ss = t; ss < SCTR; ss += 256) {
      int i = hist0[ss];
      const float* p = xb0 + 3 * i;
      float* o = cb0 + 3 * ss;
      o[0] = p[0]; o[1] = p[1]; o[2] = p[2];
      i = hist1[ss];
      p = xb1 + 3 * i;
      o = cb1 + 3 * ss;
      o[0] = p[0]; o[1] = p[1]; o[2] = p[2];
    }
    return;
  }

  // ================================ SA ===================================
  constexpr float R2 = (float)(0.2 * 0.2);
  const int t    = threadIdx.x;
  const int jb   = blockIdx.x - NFPS;
  const int half = t >> 7;
  const int ht   = t & 127;
  const int w    = ht >> 6;        // wave id within half
  const int lane = ht & 63;
  const int cid  = 2 * jb + half;
  const int b    = cid & 7;
  const int s    = cid >> 3;
  const int bid  = b * SCTR + s;
  const float* xb = xyzs + (size_t)b * NPTS * 3;

  float* in_  = smem + half * 4352;          // [k][c] stride 68, col 67 zero pad
  float* y_   = in_ + 2176;                  // [k][c] stride 68
  int*   gidx = (int*)(smem + 8704) + half * KNN;
  float* csl  = smem + 8768 + half * 4;

  // ---- wait for our center's index mailbox; coords from immutable input ----
  if (ht == 0) {
    int i0 = 0;
    if (s > 0) {
      const unsigned* rp = ring + b * SCTR + s;
      unsigned v;
      while (!((v = __hip_atomic_load(rp, __ATOMIC_RELAXED,
                                      __HIP_MEMORY_SCOPE_AGENT)) & 0x80000000u))
        __builtin_amdgcn_s_sleep(32);
      i0 = (int)(v & 0x1FFFu);
    }
    const float* cg = xb + 3 * i0;           // input data: always coherent
    csl[0] = cg[0]; csl[1] = cg[1]; csl[2] = cg[2];
  }
  __syncthreads();
  const float cx = csl[0], cy = csl[1], cz = csl[2];
  const float sc = sumsq3(cx, cy, cz);

  // ---- ball query (both waves of the half identical; dup writes benign) ----
  int cnt = 0;
  for (int base = 0; base < NPTS && cnt < KNN; base += 64) {
    int n = base + lane;
    float x = xb[n*3+0], y = xb[n*3+1], z = xb[n*3+2];
    float sx = sumsq3(x, y, z);
    float d2 = bq_d2(sc, sx, cx, cy, cz, x, y, z);
    bool within = (d2 <= R2);
    unsigned long long mk = __ballot(within);
    int rank = __popcll(mk & ((1ull << lane) - 1ull));
    int slot = cnt + rank;
    if (within && slot < KNN) gidx[slot] = n;
    cnt += (int)__popcll(mk);
  }
  if (cnt > KNN) cnt = KNN;
  __syncthreads();

  // ---- gather: in_[k][0..2]=xyz-c, [3..66]=feats, [67]=0 pad ----
#pragma unroll 4
  for (int k2 = 0; k2 < 16; ++k2) {
    int k = 2*k2 + w;
    int gk = (k < cnt) ? gidx[k] : -1;
    float fv = 0.f, xv = 0.f;
    if (gk >= 0) {
      fv = feats[((size_t)b * NPTS + gk) * NF + lane];
      if (lane < 3) xv = xb[gk*3 + lane] - csl[lane];  // exact single op
    }
    in_[k*68 + 3 + lane] = fv;
    if (lane < 3) in_[k*68 + lane] = xv;
    if (lane == 3) in_[k*68 + 67] = 0.f;
  }
  __syncthreads();

  const int g  = lane >> 3;        // k-group: k = 4g..4g+3
  const int h  = lane & 7;         // o-subgroup
  const int ob = w*32 + 4*h;       // wave's o-base for L1/L2
  const float* w1T = wT;                  // [67][64]
  const float* w2T = wT + 67*64;          // [64][64]
  const float* w3T = wT + 67*64 + 64*64;  // [64][128]

// One c-column: 16 fmas, a-scalars from the chunk's float4s.
#define FMA_COL(AS0, AS1, AS2, AS3, WV)                                      \
  do {                                                                       \
    acc[0][0]=fmaf(AS0, WV.x, acc[0][0]); acc[0][1]=fmaf(AS0, WV.y, acc[0][1]); \
    acc[0][2]=fmaf(AS0, WV.z, acc[0][2]); acc[0][3]=fmaf(AS0, WV.w, acc[0][3]); \
    acc[1][0]=fmaf(AS1, WV.x, acc[1][0]); acc[1][1]=fmaf(AS1, WV.y, acc[1][1]); \
    acc[1][2]=fmaf(AS1, WV.z, acc[1][2]); acc[1][3]=fmaf(AS1, WV.w, acc[1][3]); \
    acc[2][0]=fmaf(AS2, WV.x, acc[2][0]); acc[2][1]=fmaf(AS2, WV.y, acc[2][1]); \
    acc[2][2]=fmaf(AS2, WV.z, acc[2][2]); acc[2][3]=fmaf(AS2, WV.w, acc[2][3]); \
    acc[3][0]=fmaf(AS3, WV.x, acc[3][0]); acc[3][1]=fmaf(AS3, WV.y, acc[3][1]); \
    acc[3][2]=fmaf(AS3, WV.z, acc[3][2]); acc[3][3]=fmaf(AS3, WV.w, acc[3][3]); \
  } while (0)

// One 4-c chunk: 4 ds_read_b128 (a by k), 4 global float4 (w rows), 64 fmas.
#define MLP_CHUNK(SRC, WBASE, WSTRIDE, WOFF)                                 \
  do {                                                                       \
    float4 a0 = *(const float4*)((SRC) + (4*g+0)*68 + c0);                   \
    float4 a1 = *(const float4*)((SRC) + (4*g+1)*68 + c0);                   \
    float4 a2 = *(const float4*)((SRC) + (4*g+2)*68 + c0);                   \
    float4 a3 = *(const float4*)((SRC) + (4*g+3)*68 + c0);                   \
    float4 wv0 = *(const float4*)(WBASE + (c0+0)*(WSTRIDE) + (WOFF));        \
    float4 wv1 = *(const float4*)(WBASE + (c0+1)*(WSTRIDE) + (WOFF));        \
    float4 wv2 = *(const float4*)(WBASE + (c0+2)*(WSTRIDE) + (WOFF));        \
    float4 wv3 = *(const float4*)(WBASE + (c0+3)*(WSTRIDE) + (WOFF));        \
    FMA_COL(a0.x, a1.x, a2.x, a3.x, wv0);                                    \
    FMA_COL(a0.y, a1.y, a2.y, a3.y, wv1);                                    \
    FMA_COL(a0.z, a1.z, a2.z, a3.z, wv2);                                    \
    FMA_COL(a0.w, a1.w, a2.w, a3.w, wv3);                                    \
  } while (0)

  // ---- Layer 1: 67 -> 64 (K padded to 68; col67=0 x w2T-row0 = exact no-op) ----
  {
    float acc[4][4];
#pragma unroll
    for (int i=0;i<4;++i)
#pragma unroll
      for (int j=0;j<4;++j) acc[i][j]=0.f;
#pragma unroll 2
    for (int c0 = 0; c0 < 68; c0 += 4) {
      MLP_CHUNK(in_, w1T, 64, ob);
    }
    float scl[4], shf[4];
#pragma unroll
    for (int j=0;j<4;++j) {
      int o = ob + j;
      float r = g1[o] * rsqrtf(v1[o] + 1e-5f);
      scl[j] = r;
      shf[j] = (b1[o] - m1[o]) * r + bt1[o];
    }
#pragma unroll
    for (int i=0;i<4;++i) {
      float4 out;
      out.x = fmaxf(fmaf(acc[i][0], scl[0], shf[0]), 0.f);
      out.y = fmaxf(fmaf(acc[i][1], scl[1], shf[1]), 0.f);
      out.z = fmaxf(fmaf(acc[i][2], scl[2], shf[2]), 0.f);
      out.w = fmaxf(fmaf(acc[i][3], scl[3], shf[3]), 0.f);
      *(float4*)(y_ + (4*g+i)*68 + ob) = out;   // ds_write_b128
    }
  }
  __syncthreads();

  // ---- Layer 2: 64 -> 64 (reads y_, writes in_ o-half) ----
  {
    float acc[4][4];
#pragma unroll
    for (int i=0;i<4;++i)
#pragma unroll
      for (int j=0;j<4;++j) acc[i][j]=0.f;
#pragma unroll 2
    for (int c0 = 0; c0 < 64; c0 += 4) {
      MLP_CHUNK(y_, w2T, 64, ob);
    }
    float scl[4], shf[4];
#pragma unroll
    for (int j=0;j<4;++j) {
      int o = ob + j;
      float r = g2[o] * rsqrtf(v2[o] + 1e-5f);
      scl[j] = r;
      shf[j] = (b2[o] - m2[o]) * r + bt2[o];
    }
    __syncthreads();  // all y_ reads done before in_ overwrite (cross-wave)
#pragma unroll
    for (int i=0;i<4;++i) {
      float4 out;
      out.x = fmaxf(fmaf(acc[i][0], scl[0], shf[0]), 0.f);
      out.y = fmaxf(fmaf(acc[i][1], scl[1], shf[1]), 0.f);
      out.z = fmaxf(fmaf(acc[i][2], scl[2], shf[2]), 0.f);
      out.w = fmaxf(fmaf(acc[i][3], scl[3], shf[3]), 0.f);
      *(float4*)(in_ + (4*g+i)*68 + ob) = out;   // ds_write_b128
    }
  }
  __syncthreads();

  // ---- Layer 3: 64 -> 128; wave w owns o in [w*64, w*64+64) via 2 passes ----
  for (int p = 0; p < 2; ++p) {
    const int o3 = w*64 + p*32 + 4*h;
    float acc[4][4];
#pragma unroll
    for (int i=0;i<4;++i)
#pragma unroll
      for (int j=0;j<4;++j) acc[i][j]=0.f;
#pragma unroll 2
    for (int c0 = 0; c0 < 64; c0 += 4) {
      MLP_CHUNK(in_, w3T, 128, o3);
    }
    float scl[4], shf[4];
#pragma unroll
    for (int j=0;j<4;++j) {
      int o = o3 + j;
      float r = g3[o] * rsqrtf(v3[o] + 1e-5f);
      scl[j] = r;
      shf[j] = (b3[o] - m3[o]) * r + bt3[o];
    }
    float vm[4];
#pragma unroll
    for (int j=0;j<4;++j) {
      float q0 = fmaxf(fmaf(acc[0][j], scl[j], shf[j]), 0.f);
      float q1 = fmaxf(fmaf(acc[1][j], scl[j], shf[j]), 0.f);
      float q2 = fmaxf(fmaf(acc[2][j], scl[j], shf[j]), 0.f);
      float q3 = fmaxf(fmaf(acc[3][j], scl[j], shf[j]), 0.f);
      vm[j] = fmaxf(fmaxf(q0,q1), fmaxf(q2,q3));
    }
#pragma unroll
    for (int mk = 8; mk < 64; mk <<= 1) {
#pragma unroll
      for (int j=0;j<4;++j) vm[j] = fmaxf(vm[j], __shfl_xor(vm[j], mk));
    }
    if (g == 0) {
      float* dst = out_feats + (size_t)bid*128 + o3;
      *(float4*)dst = make_float4(vm[0], vm[1], vm[2], vm[3]);
    }
  }
#undef MLP_CHUNK
#undef FMA_COL
}

// ---------------------------------------------------------------------------
extern "C" void kernel_launch(void* const* d_in, const int* in_sizes, int n_in,
                              void* d_out, int out_size, void* d_ws, size_t ws_size,
                              hipStream_t stream) {
  const float* xyzs  = (const float*)d_in[0];
  const float* feats = (const float*)d_in[1];
  const float* w1  = (const float*)d_in[2];
  const float* b1  = (const float*)d_in[3];
  const float* g1  = (const float*)d_in[4];
  const float* bt1 = (const float*)d_in[5];
  const float* m1  = (const float*)d_in[6];
  const float* v1  = (const float*)d_in[7];
  const float* w2  = (const float*)d_in[8];
  const float* b2  = (const float*)d_in[9];
  const float* g2  = (const float*)d_in[10];
  const float* bt2 = (const float*)d_in[11];
  const float* m2  = (const float*)d_in[12];
  const float* v2  = (const float*)d_in[13];
  const float* w3  = (const float*)d_in[14];
  const float* b3  = (const float*)d_in[15];
  const float* g3  = (const float*)d_in[16];
  const float* bt3 = (const float*)d_in[17];
  const float* m3  = (const float*)d_in[18];
  const float* v3  = (const float*)d_in[19];

  float* out       = (float*)d_out;
  float* centers   = out;                          // [8][2048][3]
  float* out_feats = out + (size_t)NB * SCTR * 3;  // [8][2048][128]
  float* wT        = (float*)d_ws;                 // 16576 floats
  unsigned* ring   = (unsigned*)((float*)d_ws + WT_FLOATS);  // [8][2048] u32

  // Kernel 0: transpose weights + zero ring (stream-ordered).
  hipLaunchKernelGGL(init_kernel, dim3(65), dim3(256), 0, stream,
                     w1, w2, w3, wT, ring);
  // Mega kernel: 4 paired FPS producer blocks (first!) + 8192 sa consumers.
  hipLaunchKernelGGL(mega_kernel, dim3(NFPS + NB * SCTR / 2), dim3(256), 0, stream,
                     xyzs, feats, centers, wT, ring,
                     b1, g1, bt1, m1, v1,
                     b2, g2, bt2, m2, v2,
                     b3, g3, bt3, m3, v3,
                     out_feats);
}

// Round 8
// 3095.029 us; speedup vs baseline: 1.1084x; 1.1084x over previous
//
#include <hip/hip_runtime.h>

// PointNet++ SetAbstraction: FPS -> ball query -> grouped MLP(67->64->64->128, BN+ReLU) -> maxpool
// B=8, N=8192, S=2048, K=32, F=64.
//
// d_out: [8][2048][3] center_xyzs then [8][2048][128] center_feats (fp32).
// d_ws: 16576 floats transposed weights + u32 ring[8][2048] (64KB) mailboxes.
//
// EXACTNESS INVARIANTS (validated R4..R22: absmax 7.8e-3 < 5.4e-2):
//   - discrete-decision math contraction-free (contract(off) helpers).
//   - np.sum last-axis n=3: FORWARD plain adds (x0+x1)+x2  [FPS dist, |c|^2, |x|^2]
//   - einsum dot: ascending FMA chain fma(c2,x2, fma(c1,x1, c0*x0))  [ball query]
//   - FPS argmax: u64 key (float_bits(bv)<<13)|(8191-idx); TOTAL order.
//   - v2f ops round per-half identically to scalar (R9/R10-validated).
//   - MLP accumulation order ascending-c preserved across layout changes.
//   - R20: consumers read centers from xyzs[b][i0] — bit-identical to mirror.
//   - R21: quad-max argmax == old 32-link chain bit-for-bit (R6 PASS).
//   - R22: winner coords from global xyzs[3*i0] == old LDS mirror bits.
//   - R23 (this round): wave-split chains change WHICH WAVES run each batch's
//     chain, not its math — per-chain code is the R6 body verbatim with
//     tc = t&255 in place of t. DPP reductions are intra-wave (lane = tc&63
//     = t&63). Shared block barrier is a superset of the per-chain barrier.
//
// PERF LESSONS (measured):
//   R5: dynamically-indexed per-thread arrays get LDS-demoted — named/unrolled only.
//   R6/R7: __shfl_* lowers to ds_permute (LDS pipe) — use DPP for reductions.
//   R8..R11: FPS 1-wave-per-SIMD per chain best; barrier cost scales with waves.
//   R13/R14: KEEP fps_sqdist_v2 + fminf update order EXACTLY as-is.
//   R16: producer-consumer fusion works structurally (mega dur tracks FPS).
//   R17: co-residency interference REFUTED; setprio(3) suffices.
//   R18: vmem stores in the FPS loop pay ack latency at the next s_barrier.
//   R19/R20: relaxed 4B self-validating mailboxes (no ordering requirement).
//   R21: FPS iter is latency-bound (~790cyc issue vs ~2150 measured); chain
//       32->8 links won 105us (R6 = 1879us mega, 1914 total).
//   R22-FAILED: static ILP-2 (two chains in ONE wave) -> compiler refused
//       ~320 VGPRs, SANK the coord loads into the loop (VGPR=148, VALUBusy
//       12.5->6.9, dur x1.8). Register allocation vetoes single-wave ILP.
//   R23 (this round): TLP-2 instead — 512-thr FPS blocks, waves 0-3 = chain A
//       (batch 2bi), waves 4-7 = chain B (batch 2bi+1). Wave i -> SIMD i&3:
//       each SIMD hosts one wave of EACH chain; HW scheduler fills chain-A's
//       serial tail with chain-B's distance issue. Per-wave footprint = R6's
//       proven ~132 VGPR (coords stay register-resident). launch_bounds
//       (512,2) caps VGPR at 256. No mirror; LDS 70KB union (SA: 4 halves).

#define NPTS 8192
#define SCTR 2048
#define NB   8
#define NFPS 4                                // FPS blocks (2 chains each)
#define KNN  32
#define NF   64
#define WT_FLOATS (67*64 + 64*64 + 64*128)   // 16576
#define RING_U32  (NB * SCTR)                 // 16384

typedef float v2f __attribute__((ext_vector_type(2)));

// d = (dx*dx + dy*dy) + dz*dz for TWO points, exact fp32 mul/add order,
// NO contraction. KEEP THIS SOURCE FORM (R13/R14: fastest measured variant).
__device__ __forceinline__ v2f fps_sqdist_v2(v2f px, v2f py, v2f pz,
                                             v2f lx, v2f ly, v2f lz) {
#pragma clang fp contract(off)
  v2f dx = px - lx;
  v2f dy = py - ly;
  v2f dz = pz - lz;
  v2f xx = dx * dx;
  v2f yy = dy * dy;
  v2f zz = dz * dz;
  return (xx + yy) + zz;
}

// (x*x + y*y) + z*z, NO contraction (np.sum forward order, n=3).
__device__ __forceinline__ float sumsq3(float x, float y, float z) {
#pragma clang fp contract(off)
  return (x * x + y * y) + z * z;
}

// Ball-query expanded form: (sc + sx) - 2*dot, NO contraction on the adds.
__device__ __forceinline__ float bq_d2(float sc, float sx,
                                       float cx, float cy, float cz,
                                       float x, float y, float z) {
#pragma clang fp contract(off)
  float dt = fmaf(cz, z, fmaf(cy, y, cx * x));
  return (sc + sx) - 2.0f * dt;
}

// u64 max with the partner lane's key fetched via DPP (VALU pipe, no LDS).
template <int CTRL>
__device__ __forceinline__ unsigned long long kmax_dpp(unsigned long long k) {
  int lo = (int)(unsigned int)(k & 0xFFFFFFFFull);
  int hi = (int)(unsigned int)(k >> 32);
  int slo = __builtin_amdgcn_update_dpp(lo, lo, CTRL, 0xF, 0xF, false);
  int shi = __builtin_amdgcn_update_dpp(hi, hi, CTRL, 0xF, 0xF, false);
  unsigned long long sk =
      ((unsigned long long)(unsigned int)shi << 32) | (unsigned int)slo;
  return sk > k ? sk : k;
}

// ---------------------------------------------------------------------------
// Kernel 0: weight transpose + ring reset (stream-ordered; re-zeroes the ring
// on every graph replay BEFORE the mega kernel runs).
// ---------------------------------------------------------------------------
__global__ __launch_bounds__(256) void init_kernel(
    const float* __restrict__ w1, const float* __restrict__ w2,
    const float* __restrict__ w3, float* __restrict__ wT,
    unsigned* __restrict__ ring)
{
  const int t = threadIdx.x;
  int idx = blockIdx.x * 256 + t;
  if (idx < RING_U32) ring[idx] = 0u;   // bit31 clear = empty
  if (idx < 67*64) {
    int c = idx >> 6, o = idx & 63;
    wT[idx] = w1[o*67 + c];
  } else if (idx < 67*64 + 64*64) {
    int r = idx - 67*64; int c = r >> 6, o = r & 63;
    wT[idx] = w2[o*64 + c];
  } else if (idx < 67*64 + 64*64 + 64*128) {
    int r = idx - (67*64 + 64*64); int c = r >> 7, o = r & 127;
    wT[idx] = w3[o*64 + c];
  }
}

// ---------------------------------------------------------------------------
// Mega kernel (512 threads). Blocks 0..3: FPS, waves 0-3 = chain(batch 2bi),
// waves 4-7 = chain(batch 2bi+1). Blocks 4..4099: sa consumers, four
// 128-thread halves, cid = 4*(blk-4)+half, s-major (b=cid&7, s=cid>>3).
// Shared LDS (17552 floats = 70,208 B):
//   FPS: hist0(int)[0..2047] hist1(int)[2048..4095]
//        redk(u64[ch][pb][4]) at floats[4096..4127]
//   SA : in_/y_ halves 0..3 [0..17407]; gidx(int 4x32)[17408..17535];
//        csl [17536..17551]
// ---------------------------------------------------------------------------
__global__ __launch_bounds__(512, 2) void mega_kernel(
    const float* __restrict__ xyzs, const float* __restrict__ feats,
    float* centers, const float* __restrict__ wT, unsigned* ring,
    const float* __restrict__ b1, const float* __restrict__ g1, const float* __restrict__ bt1,
    const float* __restrict__ m1, const float* __restrict__ v1,
    const float* __restrict__ b2, const float* __restrict__ g2, const float* __restrict__ bt2,
    const float* __restrict__ m2, const float* __restrict__ v2,
    const float* __restrict__ b3, const float* __restrict__ g3, const float* __restrict__ bt3,
    const float* __restrict__ m3, const float* __restrict__ v3,
    float* out_feats)
{
  __shared__ __align__(16) float smem[17552];

  if (blockIdx.x < NFPS) {
    // ==================== FPS (two chains on split waves) =================
    __builtin_amdgcn_s_setprio(3);
    const int bi = blockIdx.x;
    const int t  = threadIdx.x;
    const int ch = t >> 8;          // chain 0 = waves 0-3, chain 1 = waves 4-7
    const int tc = t & 255;         // thread-in-chain (lane = tc&63 = t&63)
    const int t4 = 4 * tc;
    const int b  = 2*bi + ch;
    const float* xb = xyzs + (size_t)b * NPTS * 3;
    unsigned* ring_b = ring + b * SCTR;
    float* cb_ = centers + (size_t)b * SCTR * 3;
    int* hist = (int*)smem + ch * 2048;                               // [2048]
    unsigned long long* redk =
        (unsigned long long*)(smem + 4096) + ch * 8;                  // [pb][4]

    // 32 loop-invariant points (8 quads strided 1024) in NAMED registers,
    // loaded from global (AoS 48B/thread/quad). Proven register-resident at
    // this per-wave footprint (R1/R2/R5: VGPR 128-132, loads hoisted).
#define LOADQ(QX, QY, QZ, QOFF)                                               \
    { const float4* p_ = (const float4*)(xb + (size_t)3 * ((QOFF) + t4));     \
      float4 l0 = p_[0], l1 = p_[1], l2 = p_[2];                              \
      QX = make_float4(l0.x, l0.w, l1.z, l2.y);                               \
      QY = make_float4(l0.y, l1.x, l1.w, l2.z);                               \
      QZ = make_float4(l0.z, l1.y, l2.x, l2.w); }

    float4 xA, yA, zA, xB, yB, zB, xC, yC, zC, xD, yD, zD;
    float4 xE, yE, zE, xF, yF, zF, xG, yG, zG, xH, yH, zH;
    LOADQ(xA, yA, zA, 0);    LOADQ(xB, yB, zB, 1024);
    LOADQ(xC, yC, zC, 2048); LOADQ(xD, yD, zD, 3072);
    LOADQ(xE, yE, zE, 4096); LOADQ(xF, yF, zF, 5120);
    LOADQ(xG, yG, zG, 6144); LOADQ(xH, yH, zH, 7168);
#undef LOADQ

    float4 mA = make_float4(1e10f,1e10f,1e10f,1e10f);
    float4 mB = mA, mC = mA, mD = mA, mE = mA, mF = mA, mG = mA, mH = mA;

    if (tc == 0) hist[0] = 0;       // reference: first center is index 0
    float lx = xb[0], ly = xb[1], lz = xb[2];
    int stash = 0;                  // lane tc<16: winner index for s%16 == tc

// R21 quad-max body (verbatim math): min-updates + per-quad fmax tree +
// quad chain link (strict >). Distance source form UNCHANGED.
#define FPS_QUAD(QX, QY, QZ, MV, QID, BV, BQ)                                   \
  do {                                                                          \
    v2f d;                                                                      \
    d = fps_sqdist_v2((v2f){QX.x,QX.y}, (v2f){QY.x,QY.y}, (v2f){QZ.x,QZ.y},     \
                      lxv, lyv, lzv);                                           \
    MV.x = fminf(MV.x, d.x);                                                    \
    MV.y = fminf(MV.y, d.y);                                                    \
    d = fps_sqdist_v2((v2f){QX.z,QX.w}, (v2f){QY.z,QY.w}, (v2f){QZ.z,QZ.w},     \
                      lxv, lyv, lzv);                                           \
    MV.z = fminf(MV.z, d.x);                                                    \
    MV.w = fminf(MV.w, d.y);                                                    \
    float qm_ = fmaxf(fmaxf(MV.x, MV.y), fmaxf(MV.z, MV.w));                    \
    if (qm_ > BV) { BV = qm_; BQ = (QID); }                                     \
  } while (0)

    for (int s = 1; s < SCTR; ++s) {
      const int pb = s & 1;          // ping-pong slot set (WAR across iters)
      float bv0 = -1.0f, bv1 = -1.0f; int bq0 = 0, bq1 = 4;
      {
        v2f lxv = {lx, lx}, lyv = {ly, ly}, lzv = {lz, lz};
        FPS_QUAD(xA, yA, zA, mA, 0, bv0, bq0);
        FPS_QUAD(xB, yB, zB, mB, 1, bv0, bq0);
        FPS_QUAD(xC, yC, zC, mC, 2, bv0, bq0);
        FPS_QUAD(xD, yD, zD, mD, 3, bv0, bq0);
        FPS_QUAD(xE, yE, zE, mE, 4, bv1, bq1);
        FPS_QUAD(xF, yF, zF, mF, 5, bv1, bq1);
        FPS_QUAD(xG, yG, zG, mG, 6, bv1, bq1);
        FPS_QUAD(xH, yH, zH, mH, 7, bv1, bq1);
      }
      float bv = bv0; int bq = bq0;
      if (bv1 > bv0) { bv = bv1; bq = bq1; }   // chain1 quads all higher-index

      // post-chain reconstruction (R21): depth-3 select tree + first-==.
      float4 s0_ = (bq & 1) ? mB : mA;
      float4 s1_ = (bq & 1) ? mD : mC;
      float4 s2_ = (bq & 1) ? mF : mE;
      float4 s3_ = (bq & 1) ? mH : mG;
      float4 p0_ = (bq & 2) ? s1_ : s0_;
      float4 p1_ = (bq & 2) ? s3_ : s2_;
      float4 mq_ = (bq & 4) ? p1_ : p0_;
      int j_ = (bv == mq_.x) ? 0 : ((bv == mq_.y) ? 1 : ((bv == mq_.z) ? 2 : 3));
      int bg = (bq << 10) + t4 + j_;

      unsigned long long key =
          ((unsigned long long)__float_as_uint(bv) << 13) |
          (unsigned long long)(8191 - bg);

      key = kmax_dpp<0x111>(key);   // row_shr:1
      key = kmax_dpp<0x112>(key);   // row_shr:2
      key = kmax_dpp<0x114>(key);   // row_shr:4
      key = kmax_dpp<0x118>(key);   // row_shr:8
      key = kmax_dpp<0x142>(key);   // row_bcast:15
      key = kmax_dpp<0x143>(key);   // row_bcast:31

      if ((tc & 63) == 63) redk[pb*4 + (tc >> 6)] = key;
      __syncthreads();              // block-wide: superset of per-chain sync

      unsigned long long k4 = redk[pb*4 + (tc & 3)];
      k4 = kmax_dpp<0xB1>(k4);      // quad_perm [1,0,3,2]
      k4 = kmax_dpp<0x4E>(k4);      // quad_perm [2,3,0,1]

      int i0 = 8191 - (int)(k4 & 0x1FFFull);
      const float* wp = xb + 3 * i0;   // L2-resident input: same bits as mirror
      lx = wp[0]; ly = wp[1]; lz = wp[2];
      if (tc == 0) hist[s] = i0;

      // per-lane stash; publish 16 mailboxes every 16 iters (RELAXED 4B
      // self-validating messages — R20). Ack hides under next dist block.
      if (tc < 16 && (s & 15) == tc) stash = i0;
      if ((s & 15) == 15 && tc < 16) {
        __hip_atomic_store(ring_b + (s - 15) + tc,
                           0x80000000u | (unsigned)stash,
                           __ATOMIC_RELAXED, __HIP_MEMORY_SCOPE_AGENT);
      }
    }
#undef FPS_QUAD

    // epilogue: write centers to d_out (harness only — consumers use ring).
    __syncthreads();
    for (int ss = tc; ss < SCTR; ss += 256) {
      int i = hist[ss];
      const float* p = xb + 3 * i;
      float* o = cb_ + 3 * ss;
      o[0] = p[0]; o[1] = p[1]; o[2] = p[2];
    }
    return;
  }

  // ================================ SA ===================================
  constexpr float R2 = (float)(0.2 * 0.2);
  const int t    = threadIdx.x;
  const int jb   = blockIdx.x - NFPS;
  const int half = t >> 7;         // 0..3
  const int ht   = t & 127;
  const int w    = ht >> 6;        // wave id within half
  const int lane = ht & 63;
  const int cid  = 4 * jb + half;
  const int b    = cid & 7;
  const int s    = cid >> 3;
  const int bid  = b * SCTR + s;
  const float* xb = xyzs + (size_t)b * NPTS * 3;

  float* in_  = smem + half * 4352;          // [k][c] stride 68, col 67 zero pad
  float* y_   = in_ + 2176;                  // [k][c] stride 68
  int*   gidx = (int*)(smem + 17408) + half * KNN;
  float* csl  = smem + 17536 + half * 4;

  // ---- wait for our center's index mailbox; coords from immutable input ----
  if (ht == 0) {
    int i0 = 0;
    if (s > 0) {
      const unsigned* rp = ring + b * SCTR + s;
      unsigned v;
      while (!((v = __hip_atomic_load(rp, __ATOMIC_RELAXED,
                                      __HIP_MEMORY_SCOPE_AGENT)) & 0x80000000u))
        __builtin_amdgcn_s_sleep(32);
      i0 = (int)(v & 0x1FFFu);
    }
    const float* cg = xb + 3 * i0;           // input data: always coherent
    csl[0] = cg[0]; csl[1] = cg[1]; csl[2] = cg[2];
  }
  __syncthreads();
  const float cx = csl[0], cy = csl[1], cz = csl[2];
  const float sc = sumsq3(cx, cy, cz);

  // ---- ball query (both waves of the half identical; dup writes benign) ----
  int cnt = 0;
  for (int base = 0; base < NPTS && cnt < KNN; base += 64) {
    int n = base + lane;
    float x = xb[n*3+0], y = xb[n*3+1], z = xb[n*3+2];
    float sx = sumsq3(x, y, z);
    float d2 = bq_d2(sc, sx, cx, cy, cz, x, y, z);
    bool within = (d2 <= R2);
    unsigned long long mk = __ballot(within);
    int rank = __popcll(mk & ((1ull << lane) - 1ull));
    int slot = cnt + rank;
    if (within && slot < KNN) gidx[slot] = n;
    cnt += (int)__popcll(mk);
  }
  if (cnt > KNN) cnt = KNN;
  __syncthreads();

  // ---- gather: in_[k][0..2]=xyz-c, [3..66]=feats, [67]=0 pad ----
#pragma unroll 4
  for (int k2 = 0; k2 < 16; ++k2) {
    int k = 2*k2 + w;
    int gk = (k < cnt) ? gidx[k] : -1;
    float fv = 0.f, xv = 0.f;
    if (gk >= 0) {
      fv = feats[((size_t)b * NPTS + gk) * NF + lane];
      if (lane < 3) xv = xb[gk*3 + lane] - csl[lane];  // exact single op
    }
    in_[k*68 + 3 + lane] = fv;
    if (lane < 3) in_[k*68 + lane] = xv;
    if (lane == 3) in_[k*68 + 67] = 0.f;
  }
  __syncthreads();

  const int g  = lane >> 3;        // k-group: k = 4g..4g+3
  const int h  = lane & 7;         // o-subgroup
  const int ob = w*32 + 4*h;       // wave's o-base for L1/L2
  const float* w1T = wT;                  // [67][64]
  const float* w2T = wT + 67*64;          // [64][64]
  const float* w3T = wT + 67*64 + 64*64;  // [64][128]

// One c-column: 16 fmas, a-scalars from the chunk's float4s.
#define FMA_COL(AS0, AS1, AS2, AS3, WV)                                      \
  do {                                                                       \
    acc[0][0]=fmaf(AS0, WV.x, acc[0][0]); acc[0][1]=fmaf(AS0, WV.y, acc[0][1]); \
    acc[0][2]=fmaf(AS0, WV.z, acc[0][2]); acc[0][3]=fmaf(AS0, WV.w, acc[0][3]); \
    acc[1][0]=fmaf(AS1, WV.x, acc[1][0]); acc[1][1]=fmaf(AS1, WV.y, acc[1][1]); \
    acc[1][2]=fmaf(AS1, WV.z, acc[1][2]); acc[1][3]=fmaf(AS1, WV.w, acc[1][3]); \
    acc[2][0]=fmaf(AS2, WV.x, acc[2][0]); acc[2][1]=fmaf(AS2, WV.y, acc[2][1]); \
    acc[2][2]=fmaf(AS2, WV.z, acc[2][2]); acc[2][3]=fmaf(AS2, WV.w, acc[2][3]); \
    acc[3][0]=fmaf(AS3, WV.x, acc[3][0]); acc[3][1]=fmaf(AS3, WV.y, acc[3][1]); \
    acc[3][2]=fmaf(AS3, WV.z, acc[3][2]); acc[3][3]=fmaf(AS3, WV.w, acc[3][3]); \
  } while (0)

// One 4-c chunk: 4 ds_read_b128 (a by k), 4 global float4 (w rows), 64 fmas.
#define MLP_CHUNK(SRC, WBASE, WSTRIDE, WOFF)                                 \
  do {                                                                       \
    float4 a0 = *(const float4*)((SRC) + (4*g+0)*68 + c0);                   \
    float4 a1 = *(const float4*)((SRC) + (4*g+1)*68 + c0);                   \
    float4 a2 = *(const float4*)((SRC) + (4*g+2)*68 + c0);                   \
    float4 a3 = *(const float4*)((SRC) + (4*g+3)*68 + c0);                   \
    float4 wv0 = *(const float4*)(WBASE + (c0+0)*(WSTRIDE) + (WOFF));        \
    float4 wv1 = *(const float4*)(WBASE + (c0+1)*(WSTRIDE) + (WOFF));        \
    float4 wv2 = *(const float4*)(WBASE + (c0+2)*(WSTRIDE) + (WOFF));        \
    float4 wv3 = *(const float4*)(WBASE + (c0+3)*(WSTRIDE) + (WOFF));        \
    FMA_COL(a0.x, a1.x, a2.x, a3.x, wv0);                                    \
    FMA_COL(a0.y, a1.y, a2.y, a3.y, wv1);                                    \
    FMA_COL(a0.z, a1.z, a2.z, a3.z, wv2);                                    \
    FMA_COL(a0.w, a1.w, a2.w, a3.w, wv3);                                    \
  } while (0)

  // ---- Layer 1: 67 -> 64 (K padded to 68; col67=0 x w2T-row0 = exact no-op) ----
  {
    float acc[4][4];
#pragma unroll
    for (int i=0;i<4;++i)
#pragma unroll
      for (int j=0;j<4;++j) acc[i][j]=0.f;
#pragma unroll 2
    for (int c0 = 0; c0 < 68; c0 += 4) {
      MLP_CHUNK(in_, w1T, 64, ob);
    }
    float scl[4], shf[4];
#pragma unroll
    for (int j=0;j<4;++j) {
      int o = ob + j;
      float r = g1[o] * rsqrtf(v1[o] + 1e-5f);
      scl[j] = r;
      shf[j] = (b1[o] - m1[o]) * r + bt1[o];
    }
#pragma unroll
    for (int i=0;i<4;++i) {
      float4 out;
      out.x = fmaxf(fmaf(acc[i][0], scl[0], shf[0]), 0.f);
      out.y = fmaxf(fmaf(acc[i][1], scl[1], shf[1]), 0.f);
      out.z = fmaxf(fmaf(acc[i][2], scl[2], shf[2]), 0.f);
      out.w = fmaxf(fmaf(acc[i][3], scl[3], shf[3]), 0.f);
      *(float4*)(y_ + (4*g+i)*68 + ob) = out;   // ds_write_b128
    }
  }
  __syncthreads();

  // ---- Layer 2: 64 -> 64 (reads y_, writes in_ o-half) ----
  {
    float acc[4][4];
#pragma unroll
    for (int i=0;i<4;++i)
#pragma unroll
      for (int j=0;j<4;++j) acc[i][j]=0.f;
#pragma unroll 2
    for (int c0 = 0; c0 < 64; c0 += 4) {
      MLP_CHUNK(y_, w2T, 64, ob);
    }
    float scl[4], shf[4];
#pragma unroll
    for (int j=0;j<4;++j) {
      int o = ob + j;
      float r = g2[o] * rsqrtf(v2[o] + 1e-5f);
      scl[j] = r;
      shf[j] = (b2[o] - m2[o]) * r + bt2[o];
    }
    __syncthreads();  // all y_ reads done before in_ overwrite (cross-wave)
#pragma unroll
    for (int i=0;i<4;++i) {
      float4 out;
      out.x = fmaxf(fmaf(acc[i][0], scl[0], shf[0]), 0.f);
      out.y = fmaxf(fmaf(acc[i][1], scl[1], shf[1]), 0.f);
      out.z = fmaxf(fmaf(acc[i][2], scl[2], shf[2]), 0.f);
      out.w = fmaxf(fmaf(acc[i][3], scl[3], shf[3]), 0.f);
      *(float4*)(in_ + (4*g+i)*68 + ob) = out;   // ds_write_b128
    }
  }
  __syncthreads();

  // ---- Layer 3: 64 -> 128; wave w owns o in [w*64, w*64+64) via 2 passes ----
  for (int p = 0; p < 2; ++p) {
    const int o3 = w*64 + p*32 + 4*h;
    float acc[4][4];
#pragma unroll
    for (int i=0;i<4;++i)
#pragma unroll
      for (int j=0;j<4;++j) acc[i][j]=0.f;
#pragma unroll 2
    for (int c0 = 0; c0 < 64; c0 += 4) {
      MLP_CHUNK(in_, w3T, 128, o3);
    }
    float scl[4], shf[4];
#pragma unroll
    for (int j=0;j<4;++j) {
      int o = o3 + j;
      float r = g3[o] * rsqrtf(v3[o] + 1e-5f);
      scl[j] = r;
      shf[j] = (b3[o] - m3[o]) * r + bt3[o];
    }
    float vm[4];
#pragma unroll
    for (int j=0;j<4;++j) {
      float q0 = fmaxf(fmaf(acc[0][j], scl[j], shf[j]), 0.f);
      float q1 = fmaxf(fmaf(acc[1][j], scl[j], shf[j]), 0.f);
      float q2 = fmaxf(fmaf(acc[2][j], scl[j], shf[j]), 0.f);
      float q3 = fmaxf(fmaf(acc[3][j], scl[j], shf[j]), 0.f);
      vm[j] = fmaxf(fmaxf(q0,q1), fmaxf(q2,q3));
    }
#pragma unroll
    for (int mk = 8; mk < 64; mk <<= 1) {
#pragma unroll
      for (int j=0;j<4;++j) vm[j] = fmaxf(vm[j], __shfl_xor(vm[j], mk));
    }
    if (g == 0) {
      float* dst = out_feats + (size_t)bid*128 + o3;
      *(float4*)dst = make_float4(vm[0], vm[1], vm[2], vm[3]);
    }
  }
#undef MLP_CHUNK
#undef FMA_COL
}

// ---------------------------------------------------------------------------
extern "C" void kernel_launch(void* const* d_in, const int* in_sizes, int n_in,
                              void* d_out, int out_size, void* d_ws, size_t ws_size,
                              hipStream_t stream) {
  const float* xyzs  = (const float*)d_in[0];
  const float* feats = (const float*)d_in[1];
  const float* w1  = (const float*)d_in[2];
  const float* b1  = (const float*)d_in[3];
  const float* g1  = (const float*)d_in[4];
  const float* bt1 = (const float*)d_in[5];
  const float* m1  = (const float*)d_in[6];
  const float* v1  = (const float*)d_in[7];
  const float* w2  = (const float*)d_in[8];
  const float* b2  = (const float*)d_in[9];
  const float* g2  = (const float*)d_in[10];
  const float* bt2 = (const float*)d_in[11];
  const float* m2  = (const float*)d_in[12];
  const float* v2  = (const float*)d_in[13];
  const float* w3  = (const float*)d_in[14];
  const float* b3  = (const float*)d_in[15];
  const float* g3  = (const float*)d_in[16];
  const float* bt3 = (const float*)d_in[17];
  const float* m3  = (const float*)d_in[18];
  const float* v3  = (const float*)d_in[19];

  float* out       = (float*)d_out;
  float* centers   = out;                          // [8][2048][3]
  float* out_feats = out + (size_t)NB * SCTR * 3;  // [8][2048][128]
  float* wT        = (float*)d_ws;                 // 16576 floats
  unsigned* ring   = (unsigned*)((float*)d_ws + WT_FLOATS);  // [8][2048] u32

  // Kernel 0: transpose weights + zero ring (stream-ordered).
  hipLaunchKernelGGL(init_kernel, dim3(65), dim3(256), 0, stream,
                     w1, w2, w3, wT, ring);
  // Mega kernel: 4 dual-chain FPS blocks (first!) + 4096 sa consumer blocks.
  hipLaunchKernelGGL(mega_kernel, dim3(NFPS + NB * SCTR / 4), dim3(512), 0, stream,
                     xyzs, feats, centers, wT, ring,
                     b1, g1, bt1, m1, v1,
                     b2, g2, bt2, m2, v2,
                     b3, g3, bt3, m3, v3,
                     out_feats);
}

// Round 9
// 3034.475 us; speedup vs baseline: 1.1305x; 1.0200x over previous
//
#include <hip/hip_runtime.h>

// PointNet++ SetAbstraction: FPS -> ball query -> grouped MLP(67->64->64->128, BN+ReLU) -> maxpool
// B=8, N=8192, S=2048, K=32, F=64.
//
// d_out: [8][2048][3] center_xyzs then [8][2048][128] center_feats (fp32).
// d_ws: 16576 floats transposed weights + u32 ring[8][2048] (64KB) mailboxes.
//
// EXACTNESS INVARIANTS (validated R4..R23: absmax 7.8e-3 < 5.4e-2):
//   - discrete-decision math contraction-free (contract(off) helpers).
//   - np.sum last-axis n=3: FORWARD plain adds (x0+x1)+x2  [FPS dist, |c|^2, |x|^2]
//   - einsum dot: ascending FMA chain fma(c2,x2, fma(c1,x1, c0*x0))  [ball query]
//   - FPS argmax: u64 key (float_bits(bv)<<13)|(8191-idx); TOTAL order.
//   - v2f ops round per-half identically to scalar (R9/R10-validated).
//   - MLP accumulation order ascending-c preserved across layout changes.
//   - R20: consumers read centers from xyzs[b][i0] — bit-identical to mirror.
//   - R21: quad-max argmax == old 32-link chain bit-for-bit (R6 PASS).
//   - R22: winner coords from global xyzs[3*i0] == old LDS mirror bits.
//   - R23: wave-split chains = R6 math verbatim per chain (R8 PASS).
//   - R24 (this round): PIN4 is an identity asm ("+v") — value unchanged,
//     only the allocator's freedom to rematerialize is removed.
//
// PERF LESSONS (measured):
//   R5: dynamically-indexed per-thread arrays get LDS-demoted — named/unrolled only.
//   R6/R7: __shfl_* lowers to ds_permute (LDS pipe) — use DPP for reductions.
//   R8..R11: FPS 1-wave-per-SIMD per chain best; barrier cost scales with waves.
//   R13/R14: KEEP fps_sqdist_v2 + fminf update order EXACTLY as-is.
//   R16: producer-consumer fusion works structurally (mega dur tracks FPS).
//   R17: co-residency interference REFUTED; setprio(3) suffices.
//   R18: vmem stores in the FPS loop pay ack latency at the next s_barrier.
//   R19/R20: relaxed 4B self-validating mailboxes (no ordering requirement).
//   R21: FPS iter is latency-bound (~900cyc issue vs ~2150 measured); chain
//       32->8 links won 105us (R6 = 1879us mega, 1914 total = best PASS).
//   R22-FAILED/R23-FAILED: both ILP-2 (one wave) and TLP-2 (split waves)
//       were vetoed by the REGISTER ALLOCATOR: it sank the 96 coord loads
//       into the loop (R7: VGPR 148; R8: VGPR 76, FETCH 6->10GB, VALUBusy
//       12.5->7.8, dur x1.6). launch_bounds caps were not binding — it's the
//       occupancy-maximizing remat heuristic.
//   R24 (this round): R8 structure + OPAQUE ASM PINS on the 24 coord quads
//       (ext_vector(4) + asm "+v" identity). Asm defs cannot be remat'd or
//       sunk -> allocator must keep coords resident (~160 VGPR < 256 cap).
//       This finally TESTS the TLP-2 hypothesis instead of losing to regalloc.

#define NPTS 8192
#define SCTR 2048
#define NB   8
#define NFPS 4                                // FPS blocks (2 chains each)
#define KNN  32
#define NF   64
#define WT_FLOATS (67*64 + 64*64 + 64*128)   // 16576
#define RING_U32  (NB * SCTR)                 // 16384

typedef float v2f __attribute__((ext_vector_type(2)));
typedef float v4f __attribute__((ext_vector_type(4)));

// Opaque identity: forbids rematerialization/sinking of the pinned value.
#define PIN4(V) asm volatile("" : "+v"(V))

// d = (dx*dx + dy*dy) + dz*dz for TWO points, exact fp32 mul/add order,
// NO contraction. KEEP THIS SOURCE FORM (R13/R14: fastest measured variant).
__device__ __forceinline__ v2f fps_sqdist_v2(v2f px, v2f py, v2f pz,
                                             v2f lx, v2f ly, v2f lz) {
#pragma clang fp contract(off)
  v2f dx = px - lx;
  v2f dy = py - ly;
  v2f dz = pz - lz;
  v2f xx = dx * dx;
  v2f yy = dy * dy;
  v2f zz = dz * dz;
  return (xx + yy) + zz;
}

// (x*x + y*y) + z*z, NO contraction (np.sum forward order, n=3).
__device__ __forceinline__ float sumsq3(float x, float y, float z) {
#pragma clang fp contract(off)
  return (x * x + y * y) + z * z;
}

// Ball-query expanded form: (sc + sx) - 2*dot, NO contraction on the adds.
__device__ __forceinline__ float bq_d2(float sc, float sx,
                                       float cx, float cy, float cz,
                                       float x, float y, float z) {
#pragma clang fp contract(off)
  float dt = fmaf(cz, z, fmaf(cy, y, cx * x));
  return (sc + sx) - 2.0f * dt;
}

// u64 max with the partner lane's key fetched via DPP (VALU pipe, no LDS).
template <int CTRL>
__device__ __forceinline__ unsigned long long kmax_dpp(unsigned long long k) {
  int lo = (int)(unsigned int)(k & 0xFFFFFFFFull);
  int hi = (int)(unsigned int)(k >> 32);
  int slo = __builtin_amdgcn_update_dpp(lo, lo, CTRL, 0xF, 0xF, false);
  int shi = __builtin_amdgcn_update_dpp(hi, hi, CTRL, 0xF, 0xF, false);
  unsigned long long sk =
      ((unsigned long long)(unsigned int)shi << 32) | (unsigned int)slo;
  return sk > k ? sk : k;
}

// ---------------------------------------------------------------------------
// Kernel 0: weight transpose + ring reset (stream-ordered; re-zeroes the ring
// on every graph replay BEFORE the mega kernel runs).
// ---------------------------------------------------------------------------
__global__ __launch_bounds__(256) void init_kernel(
    const float* __restrict__ w1, const float* __restrict__ w2,
    const float* __restrict__ w3, float* __restrict__ wT,
    unsigned* __restrict__ ring)
{
  const int t = threadIdx.x;
  int idx = blockIdx.x * 256 + t;
  if (idx < RING_U32) ring[idx] = 0u;   // bit31 clear = empty
  if (idx < 67*64) {
    int c = idx >> 6, o = idx & 63;
    wT[idx] = w1[o*67 + c];
  } else if (idx < 67*64 + 64*64) {
    int r = idx - 67*64; int c = r >> 6, o = r & 63;
    wT[idx] = w2[o*64 + c];
  } else if (idx < 67*64 + 64*64 + 64*128) {
    int r = idx - (67*64 + 64*64); int c = r >> 7, o = r & 127;
    wT[idx] = w3[o*64 + c];
  }
}

// ---------------------------------------------------------------------------
// Mega kernel (512 threads). Blocks 0..3: FPS, waves 0-3 = chain(batch 2bi),
// waves 4-7 = chain(batch 2bi+1). Blocks 4..4099: sa consumers, four
// 128-thread halves, cid = 4*(blk-4)+half, s-major (b=cid&7, s=cid>>3).
// Shared LDS (17552 floats = 70,208 B):
//   FPS: hist0(int)[0..2047] hist1(int)[2048..4095]
//        redk(u64[ch][pb][4]) at floats[4096..4127]
//   SA : in_/y_ halves 0..3 [0..17407]; gidx(int 4x32)[17408..17535];
//        csl [17536..17551]
// ---------------------------------------------------------------------------
__global__ __launch_bounds__(512, 2) void mega_kernel(
    const float* __restrict__ xyzs, const float* __restrict__ feats,
    float* centers, const float* __restrict__ wT, unsigned* ring,
    const float* __restrict__ b1, const float* __restrict__ g1, const float* __restrict__ bt1,
    const float* __restrict__ m1, const float* __restrict__ v1,
    const float* __restrict__ b2, const float* __restrict__ g2, const float* __restrict__ bt2,
    const float* __restrict__ m2, const float* __restrict__ v2,
    const float* __restrict__ b3, const float* __restrict__ g3, const float* __restrict__ bt3,
    const float* __restrict__ m3, const float* __restrict__ v3,
    float* out_feats)
{
  __shared__ __align__(16) float smem[17552];

  if (blockIdx.x < NFPS) {
    // ==================== FPS (two chains on split waves) =================
    __builtin_amdgcn_s_setprio(3);
    const int bi = blockIdx.x;
    const int t  = threadIdx.x;
    const int ch = t >> 8;          // chain 0 = waves 0-3, chain 1 = waves 4-7
    const int tc = t & 255;         // thread-in-chain (lane = tc&63 = t&63)
    const int t4 = 4 * tc;
    const int b  = 2*bi + ch;
    const float* xb = xyzs + (size_t)b * NPTS * 3;
    unsigned* ring_b = ring + b * SCTR;
    float* cb_ = centers + (size_t)b * SCTR * 3;
    int* hist = (int*)smem + ch * 2048;                               // [2048]
    unsigned long long* redk =
        (unsigned long long*)(smem + 4096) + ch * 8;                  // [pb][4]

    // 32 loop-invariant points (8 quads strided 1024) in NAMED registers,
    // loaded from global (AoS 48B/thread/quad) and PINNED (R24): asm defs
    // cannot be rematerialized into the loop by the register allocator.
#define LOADQ(QX, QY, QZ, QOFF)                                               \
    { const float4* p_ = (const float4*)(xb + (size_t)3 * ((QOFF) + t4));     \
      float4 l0 = p_[0], l1 = p_[1], l2 = p_[2];                              \
      QX = (v4f){l0.x, l0.w, l1.z, l2.y};                                     \
      QY = (v4f){l0.y, l1.x, l1.w, l2.z};                                     \
      QZ = (v4f){l0.z, l1.y, l2.x, l2.w};                                     \
      PIN4(QX); PIN4(QY); PIN4(QZ); }

    v4f xA, yA, zA, xB, yB, zB, xC, yC, zC, xD, yD, zD;
    v4f xE, yE, zE, xF, yF, zF, xG, yG, zG, xH, yH, zH;
    LOADQ(xA, yA, zA, 0);    LOADQ(xB, yB, zB, 1024);
    LOADQ(xC, yC, zC, 2048); LOADQ(xD, yD, zD, 3072);
    LOADQ(xE, yE, zE, 4096); LOADQ(xF, yF, zF, 5120);
    LOADQ(xG, yG, zG, 6144); LOADQ(xH, yH, zH, 7168);
#undef LOADQ

    v4f mA = (v4f){1e10f,1e10f,1e10f,1e10f};
    v4f mB = mA, mC = mA, mD = mA, mE = mA, mF = mA, mG = mA, mH = mA;

    if (tc == 0) hist[0] = 0;       // reference: first center is index 0
    float lx = xb[0], ly = xb[1], lz = xb[2];
    int stash = 0;                  // lane tc<16: winner index for s%16 == tc

// R21 quad-max body (verbatim math): min-updates + per-quad fmax tree +
// quad chain link (strict >). Distance source form UNCHANGED.
#define FPS_QUAD(QX, QY, QZ, MV, QID, BV, BQ)                                   \
  do {                                                                          \
    v2f d;                                                                      \
    d = fps_sqdist_v2((v2f){QX.x,QX.y}, (v2f){QY.x,QY.y}, (v2f){QZ.x,QZ.y},     \
                      lxv, lyv, lzv);                                           \
    MV.x = fminf(MV.x, d.x);                                                    \
    MV.y = fminf(MV.y, d.y);                                                    \
    d = fps_sqdist_v2((v2f){QX.z,QX.w}, (v2f){QY.z,QY.w}, (v2f){QZ.z,QZ.w},     \
                      lxv, lyv, lzv);                                           \
    MV.z = fminf(MV.z, d.x);                                                    \
    MV.w = fminf(MV.w, d.y);                                                    \
    float qm_ = fmaxf(fmaxf(MV.x, MV.y), fmaxf(MV.z, MV.w));                    \
    if (qm_ > BV) { BV = qm_; BQ = (QID); }                                     \
  } while (0)

    for (int s = 1; s < SCTR; ++s) {
      const int pb = s & 1;          // ping-pong slot set (WAR across iters)
      float bv0 = -1.0f, bv1 = -1.0f; int bq0 = 0, bq1 = 4;
      {
        v2f lxv = {lx, lx}, lyv = {ly, ly}, lzv = {lz, lz};
        FPS_QUAD(xA, yA, zA, mA, 0, bv0, bq0);
        FPS_QUAD(xB, yB, zB, mB, 1, bv0, bq0);
        FPS_QUAD(xC, yC, zC, mC, 2, bv0, bq0);
        FPS_QUAD(xD, yD, zD, mD, 3, bv0, bq0);
        FPS_QUAD(xE, yE, zE, mE, 4, bv1, bq1);
        FPS_QUAD(xF, yF, zF, mF, 5, bv1, bq1);
        FPS_QUAD(xG, yG, zG, mG, 6, bv1, bq1);
        FPS_QUAD(xH, yH, zH, mH, 7, bv1, bq1);
      }
      float bv = bv0; int bq = bq0;
      if (bv1 > bv0) { bv = bv1; bq = bq1; }   // chain1 quads all higher-index

      // post-chain reconstruction (R21): depth-3 select tree + first-==.
      v4f s0_ = (bq & 1) ? mB : mA;
      v4f s1_ = (bq & 1) ? mD : mC;
      v4f s2_ = (bq & 1) ? mF : mE;
      v4f s3_ = (bq & 1) ? mH : mG;
      v4f p0_ = (bq & 2) ? s1_ : s0_;
      v4f p1_ = (bq & 2) ? s3_ : s2_;
      v4f mq_ = (bq & 4) ? p1_ : p0_;
      int j_ = (bv == mq_.x) ? 0 : ((bv == mq_.y) ? 1 : ((bv == mq_.z) ? 2 : 3));
      int bg = (bq << 10) + t4 + j_;

      unsigned long long key =
          ((unsigned long long)__float_as_uint(bv) << 13) |
          (unsigned long long)(8191 - bg);

      key = kmax_dpp<0x111>(key);   // row_shr:1
      key = kmax_dpp<0x112>(key);   // row_shr:2
      key = kmax_dpp<0x114>(key);   // row_shr:4
      key = kmax_dpp<0x118>(key);   // row_shr:8
      key = kmax_dpp<0x142>(key);   // row_bcast:15
      key = kmax_dpp<0x143>(key);   // row_bcast:31

      if ((tc & 63) == 63) redk[pb*4 + (tc >> 6)] = key;
      __syncthreads();              // block-wide: superset of per-chain sync

      unsigned long long k4 = redk[pb*4 + (tc & 3)];
      k4 = kmax_dpp<0xB1>(k4);      // quad_perm [1,0,3,2]
      k4 = kmax_dpp<0x4E>(k4);      // quad_perm [2,3,0,1]

      int i0 = 8191 - (int)(k4 & 0x1FFFull);
      const float* wp = xb + 3 * i0;   // L2-resident input: same bits as mirror
      lx = wp[0]; ly = wp[1]; lz = wp[2];
      if (tc == 0) hist[s] = i0;

      // per-lane stash; publish 16 mailboxes every 16 iters (RELAXED 4B
      // self-validating messages — R20). Ack hides under next dist block.
      if (tc < 16 && (s & 15) == tc) stash = i0;
      if ((s & 15) == 15 && tc < 16) {
        __hip_atomic_store(ring_b + (s - 15) + tc,
                           0x80000000u | (unsigned)stash,
                           __ATOMIC_RELAXED, __HIP_MEMORY_SCOPE_AGENT);
      }
    }
#undef FPS_QUAD

    // epilogue: write centers to d_out (harness only — consumers use ring).
    __syncthreads();
    for (int ss = tc; ss < SCTR; ss += 256) {
      int i = hist[ss];
      const float* p = xb + 3 * i;
      float* o = cb_ + 3 * ss;
      o[0] = p[0]; o[1] = p[1]; o[2] = p[2];
    }
    return;
  }

  // ================================ SA ===================================
  constexpr float R2 = (float)(0.2 * 0.2);
  const int t    = threadIdx.x;
  const int jb   = blockIdx.x - NFPS;
  const int half = t >> 7;         // 0..3
  const int ht   = t & 127;
  const int w    = ht >> 6;        // wave id within half
  const int lane = ht & 63;
  const int cid  = 4 * jb + half;
  const int b    = cid & 7;
  const int s    = cid >> 3;
  const int bid  = b * SCTR + s;
  const float* xb = xyzs + (size_t)b * NPTS * 3;

  float* in_  = smem + half * 4352;          // [k][c] stride 68, col 67 zero pad
  float* y_   = in_ + 2176;                  // [k][c] stride 68
  int*   gidx = (int*)(smem + 17408) + half * KNN;
  float* csl  = smem + 17536 + half * 4;

  // ---- wait for our center's index mailbox; coords from immutable input ----
  if (ht == 0) {
    int i0 = 0;
    if (s > 0) {
      const unsigned* rp = ring + b * SCTR + s;
      unsigned v;
      while (!((v = __hip_atomic_load(rp, __ATOMIC_RELAXED,
                                      __HIP_MEMORY_SCOPE_AGENT)) & 0x80000000u))
        __builtin_amdgcn_s_sleep(32);
      i0 = (int)(v & 0x1FFFu);
    }
    const float* cg = xb + 3 * i0;           // input data: always coherent
    csl[0] = cg[0]; csl[1] = cg[1]; csl[2] = cg[2];
  }
  __syncthreads();
  const float cx = csl[0], cy = csl[1], cz = csl[2];
  const float sc = sumsq3(cx, cy, cz);

  // ---- ball query (both waves of the half identical; dup writes benign) ----
  int cnt = 0;
  for (int base = 0; base < NPTS && cnt < KNN; base += 64) {
    int n = base + lane;
    float x = xb[n*3+0], y = xb[n*3+1], z = xb[n*3+2];
    float sx = sumsq3(x, y, z);
    float d2 = bq_d2(sc, sx, cx, cy, cz, x, y, z);
    bool within = (d2 <= R2);
    unsigned long long mk = __ballot(within);
    int rank = __popcll(mk & ((1ull << lane) - 1ull));
    int slot = cnt + rank;
    if (within && slot < KNN) gidx[slot] = n;
    cnt += (int)__popcll(mk);
  }
  if (cnt > KNN) cnt = KNN;
  __syncthreads();

  // ---- gather: in_[k][0..2]=xyz-c, [3..66]=feats, [67]=0 pad ----
#pragma unroll 4
  for (int k2 = 0; k2 < 16; ++k2) {
    int k = 2*k2 + w;
    int gk = (k < cnt) ? gidx[k] : -1;
    float fv = 0.f, xv = 0.f;
    if (gk >= 0) {
      fv = feats[((size_t)b * NPTS + gk) * NF + lane];
      if (lane < 3) xv = xb[gk*3 + lane] - csl[lane];  // exact single op
    }
    in_[k*68 + 3 + lane] = fv;
    if (lane < 3) in_[k*68 + lane] = xv;
    if (lane == 3) in_[k*68 + 67] = 0.f;
  }
  __syncthreads();

  const int g  = lane >> 3;        // k-group: k = 4g..4g+3
  const int h  = lane & 7;         // o-subgroup
  const int ob = w*32 + 4*h;       // wave's o-base for L1/L2
  const float* w1T = wT;                  // [67][64]
  const float* w2T = wT + 67*64;          // [64][64]
  const float* w3T = wT + 67*64 + 64*64;  // [64][128]

// One c-column: 16 fmas, a-scalars from the chunk's float4s.
#define FMA_COL(AS0, AS1, AS2, AS3, WV)                                      \
  do {                                                                       \
    acc[0][0]=fmaf(AS0, WV.x, acc[0][0]); acc[0][1]=fmaf(AS0, WV.y, acc[0][1]); \
    acc[0][2]=fmaf(AS0, WV.z, acc[0][2]); acc[0][3]=fmaf(AS0, WV.w, acc[0][3]); \
    acc[1][0]=fmaf(AS1, WV.x, acc[1][0]); acc[1][1]=fmaf(AS1, WV.y, acc[1][1]); \
    acc[1][2]=fmaf(AS1, WV.z, acc[1][2]); acc[1][3]=fmaf(AS1, WV.w, acc[1][3]); \
    acc[2][0]=fmaf(AS2, WV.x, acc[2][0]); acc[2][1]=fmaf(AS2, WV.y, acc[2][1]); \
    acc[2][2]=fmaf(AS2, WV.z, acc[2][2]); acc[2][3]=fmaf(AS2, WV.w, acc[2][3]); \
    acc[3][0]=fmaf(AS3, WV.x, acc[3][0]); acc[3][1]=fmaf(AS3, WV.y, acc[3][1]); \
    acc[3][2]=fmaf(AS3, WV.z, acc[3][2]); acc[3][3]=fmaf(AS3, WV.w, acc[3][3]); \
  } while (0)

// One 4-c chunk: 4 ds_read_b128 (a by k), 4 global float4 (w rows), 64 fmas.
#define MLP_CHUNK(SRC, WBASE, WSTRIDE, WOFF)                                 \
  do {                                                                       \
    float4 a0 = *(const float4*)((SRC) + (4*g+0)*68 + c0);                   \
    float4 a1 = *(const float4*)((SRC) + (4*g+1)*68 + c0);                   \
    float4 a2 = *(const float4*)((SRC) + (4*g+2)*68 + c0);                   \
    float4 a3 = *(const float4*)((SRC) + (4*g+3)*68 + c0);                   \
    float4 wv0 = *(const float4*)(WBASE + (c0+0)*(WSTRIDE) + (WOFF));        \
    float4 wv1 = *(const float4*)(WBASE + (c0+1)*(WSTRIDE) + (WOFF));        \
    float4 wv2 = *(const float4*)(WBASE + (c0+2)*(WSTRIDE) + (WOFF));        \
    float4 wv3 = *(const float4*)(WBASE + (c0+3)*(WSTRIDE) + (WOFF));        \
    FMA_COL(a0.x, a1.x, a2.x, a3.x, wv0);                                    \
    FMA_COL(a0.y, a1.y, a2.y, a3.y, wv1);                                    \
    FMA_COL(a0.z, a1.z, a2.z, a3.z, wv2);                                    \
    FMA_COL(a0.w, a1.w, a2.w, a3.w, wv3);                                    \
  } while (0)

  // ---- Layer 1: 67 -> 64 (K padded to 68; col67=0 x w2T-row0 = exact no-op) ----
  {
    float acc[4][4];
#pragma unroll
    for (int i=0;i<4;++i)
#pragma unroll
      for (int j=0;j<4;++j) acc[i][j]=0.f;
#pragma unroll 2
    for (int c0 = 0; c0 < 68; c0 += 4) {
      MLP_CHUNK(in_, w1T, 64, ob);
    }
    float scl[4], shf[4];
#pragma unroll
    for (int j=0;j<4;++j) {
      int o = ob + j;
      float r = g1[o] * rsqrtf(v1[o] + 1e-5f);
      scl[j] = r;
      shf[j] = (b1[o] - m1[o]) * r + bt1[o];
    }
#pragma unroll
    for (int i=0;i<4;++i) {
      float4 out;
      out.x = fmaxf(fmaf(acc[i][0], scl[0], shf[0]), 0.f);
      out.y = fmaxf(fmaf(acc[i][1], scl[1], shf[1]), 0.f);
      out.z = fmaxf(fmaf(acc[i][2], scl[2], shf[2]), 0.f);
      out.w = fmaxf(fmaf(acc[i][3], scl[3], shf[3]), 0.f);
      *(float4*)(y_ + (4*g+i)*68 + ob) = out;   // ds_write_b128
    }
  }
  __syncthreads();

  // ---- Layer 2: 64 -> 64 (reads y_, writes in_ o-half) ----
  {
    float acc[4][4];
#pragma unroll
    for (int i=0;i<4;++i)
#pragma unroll
      for (int j=0;j<4;++j) acc[i][j]=0.f;
#pragma unroll 2
    for (int c0 = 0; c0 < 64; c0 += 4) {
      MLP_CHUNK(y_, w2T, 64, ob);
    }
    float scl[4], shf[4];
#pragma unroll
    for (int j=0;j<4;++j) {
      int o = ob + j;
      float r = g2[o] * rsqrtf(v2[o] + 1e-5f);
      scl[j] = r;
      shf[j] = (b2[o] - m2[o]) * r + bt2[o];
    }
    __syncthreads();  // all y_ reads done before in_ overwrite (cross-wave)
#pragma unroll
    for (int i=0;i<4;++i) {
      float4 out;
      out.x = fmaxf(fmaf(acc[i][0], scl[0], shf[0]), 0.f);
      out.y = fmaxf(fmaf(acc[i][1], scl[1], shf[1]), 0.f);
      out.z = fmaxf(fmaf(acc[i][2], scl[2], shf[2]), 0.f);
      out.w = fmaxf(fmaf(acc[i][3], scl[3], shf[3]), 0.f);
      *(float4*)(in_ + (4*g+i)*68 + ob) = out;   // ds_write_b128
    }
  }
  __syncthreads();

  // ---- Layer 3: 64 -> 128; wave w owns o in [w*64, w*64+64) via 2 passes ----
  for (int p = 0; p < 2; ++p) {
    const int o3 = w*64 + p*32 + 4*h;
    float acc[4][4];
#pragma unroll
    for (int i=0;i<4;++i)
#pragma unroll
      for (int j=0;j<4;++j) acc[i][j]=0.f;
#pragma unroll 2
    for (int c0 = 0; c0 < 64; c0 += 4) {
      MLP_CHUNK(in_, w3T, 128, o3);
    }
    float scl[4], shf[4];
#pragma unroll
    for (int j=0;j<4;++j) {
      int o = o3 + j;
      float r = g3[o] * rsqrtf(v3[o] + 1e-5f);
      scl[j] = r;
      shf[j] = (b3[o] - m3[o]) * r + bt3[o];
    }
    float vm[4];
#pragma unroll
    for (int j=0;j<4;++j) {
      float q0 = fmaxf(fmaf(acc[0][j], scl[j], shf[j]), 0.f);
      float q1 = fmaxf(fmaf(acc[1][j], scl[j], shf[j]), 0.f);
      float q2 = fmaxf(fmaf(acc[2][j], scl[j], shf[j]), 0.f);
      float q3 = fmaxf(fmaf(acc[3][j], scl[j], shf[j]), 0.f);
      vm[j] = fmaxf(fmaxf(q0,q1), fmaxf(q2,q3));
    }
#pragma unroll
    for (int mk = 8; mk < 64; mk <<= 1) {
#pragma unroll
      for (int j=0;j<4;++j) vm[j] = fmaxf(vm[j], __shfl_xor(vm[j], mk));
    }
    if (g == 0) {
      float* dst = out_feats + (size_t)bid*128 + o3;
      *(float4*)dst = make_float4(vm[0], vm[1], vm[2], vm[3]);
    }
  }
#undef MLP_CHUNK
#undef FMA_COL
}

// ---------------------------------------------------------------------------
extern "C" void kernel_launch(void* const* d_in, const int* in_sizes, int n_in,
                              void* d_out, int out_size, void* d_ws, size_t ws_size,
                              hipStream_t stream) {
  const float* xyzs  = (const float*)d_in[0];
  const float* feats = (const float*)d_in[1];
  const float* w1  = (const float*)d_in[2];
  const float* b1  = (const float*)d_in[3];
  const float* g1  = (const float*)d_in[4];
  const float* bt1 = (const float*)d_in[5];
  const float* m1  = (const float*)d_in[6];
  const float* v1  = (const float*)d_in[7];
  const float* w2  = (const float*)d_in[8];
  const float* b2  = (const float*)d_in[9];
  const float* g2  = (const float*)d_in[10];
  const float* bt2 = (const float*)d_in[11];
  const float* m2  = (const float*)d_in[12];
  const float* v2  = (const float*)d_in[13];
  const float* w3  = (const float*)d_in[14];
  const float* b3  = (const float*)d_in[15];
  const float* g3  = (const float*)d_in[16];
  const float* bt3 = (const float*)d_in[17];
  const float* m3  = (const float*)d_in[18];
  const float* v3  = (const float*)d_in[19];

  float* out       = (float*)d_out;
  float* centers   = out;                          // [8][2048][3]
  float* out_feats = out + (size_t)NB * SCTR * 3;  // [8][2048][128]
  float* wT        = (float*)d_ws;                 // 16576 floats
  unsigned* ring   = (unsigned*)((float*)d_ws + WT_FLOATS);  // [8][2048] u32

  // Kernel 0: transpose weights + zero ring (stream-ordered).
  hipLaunchKernelGGL(init_kernel, dim3(65), dim3(256), 0, stream,
                     w1, w2, w3, wT, ring);
  // Mega kernel: 4 dual-chain FPS blocks (first!) + 4096 sa consumer blocks.
  hipLaunchKernelGGL(mega_kernel, dim3(NFPS + NB * SCTR / 4), dim3(512), 0, stream,
                     xyzs, feats, centers, wT, ring,
                     b1, g1, bt1, m1, v1,
                     b2, g2, bt2, m2, v2,
                     b3, g3, bt3, m3, v3,
                     out_feats);
}

// Round 10
// 1917.289 us; speedup vs baseline: 1.7893x; 1.5827x over previous
//
#include <hip/hip_runtime.h>

// PointNet++ SetAbstraction: FPS -> ball query -> grouped MLP(67->64->64->128, BN+ReLU) -> maxpool
// B=8, N=8192, S=2048, K=32, F=64.
//
// d_out: [8][2048][3] center_xyzs then [8][2048][128] center_feats (fp32).
// d_ws: 16576 floats transposed weights + u32 ring[8][2048] (64KB) index
//       mailboxes. Total ws use = 131,840 B.
//
// FINAL STATE (R25): revert to the best-measured kernel (R6 structure,
// 1914.5us total, PASS). The TLP/ILP-2 FPS axis is conclusively
// compiler-blocked (see lessons R22-R24); serial FPS chain is the floor.
//
// EXACTNESS INVARIANTS (validated R4..R21: absmax 7.8e-3 < 5.4e-2):
//   - discrete-decision math contraction-free (contract(off) helpers).
//   - np.sum last-axis n=3: FORWARD plain adds (x0+x1)+x2  [FPS dist, |c|^2, |x|^2]
//   - einsum dot: ascending FMA chain fma(c2,x2, fma(c1,x1, c0*x0))  [ball query]
//   - FPS argmax: u64 key (float_bits(bv)<<13)|(8191-idx); TOTAL order.
//   - v2f ops round per-half identically to scalar (R9/R10-validated).
//   - MLP accumulation order ascending-c preserved across layout changes.
//   - R20: consumers read centers from xyzs[b][i0] — bit-identical to mirror.
//   - R21: quad-max argmax (per-quad fmax tree + quad chain + post-chain
//     reconstruction) == old 32-link chain bit-for-bit: fmaxf returns an
//     operand bit-exactly; all minds >= +0 (x*x sums, 1e10 init; no -0/NaN);
//     strict > across ascending-index quads keeps FIRST max quad (dual
//     chains 0-3 / 4-7); first-== within quad keeps FIRST max elem.
//
// PERF LESSONS (measured):
//   R5: dynamically-indexed per-thread arrays get LDS-demoted — named/unrolled only.
//   R6/R7: __shfl_* lowers to ds_permute (LDS pipe) — use DPP for reductions.
//   R8..R11: FPS 256thr/1-wave-per-SIMD best; barrier cost scales with waves.
//   R13/R14: FPS dist-loop source form: v2f-source fastest. KEEP fps_sqdist_v2
//       and the fminf update order EXACTLY as-is.
//   R13: sa o-split 2 waves WIN. R14: +LDS b128 (stride 68, 4-c chunks).
//   R16: producer-consumer fusion works structurally (mega dur tracks FPS).
//   R17: co-residency interference REFUTED; setprio(3) suffices.
//   R18: vmem stores inside the FPS loop pay their ack latency at the next
//       s_barrier (hipcc drains vmcnt(0) before every barrier) — batch them.
//   R19: handoff needs formal ordering + slack, OR no ordering requirement.
//   R20: relaxed 4B self-validating mailboxes (simplest correct protocol);
//       agent-RELEASE-wbl2 theory refuted (null perf delta).
//   R21: FPS iter is latency-bound on the serial argmax chain at 1 wave/SIMD.
//       Chain 32->8 links: -105us (mega 1984->1879; total 1914.5 = BEST).
//   R22/R23/R24 ALL FAILED — 2-chains-per-CU FPS is compiler-blocked:
//       R22 (ILP-2, one wave): allocator refused ~320 VGPR, SANK coord loads
//         into the loop (VGPR 148, dur x1.8).
//       R23 (TLP-2, split waves): same remat (VGPR 76, FETCH 6->10GB).
//       R24 (TLP-2 + asm "+v" pins): allocator SPILLED the pinned tuples to
//         scratch instead (VGPR 80, FETCH 10.4GB) — pins stop remat, not
//         spill. Occupancy heuristic wins at HIP source level. STOP AXIS.

#define NPTS 8192
#define SCTR 2048
#define NB   8
#define KNN  32
#define NF   64
#define WT_FLOATS (67*64 + 64*64 + 64*128)   // 16576
#define RING_U32  (NB * SCTR)                 // 16384

typedef float v2f __attribute__((ext_vector_type(2)));

// d = (dx*dx + dy*dy) + dz*dz for TWO points, exact fp32 mul/add order,
// NO contraction. KEEP THIS SOURCE FORM (R13/R14: fastest measured variant).
__device__ __forceinline__ v2f fps_sqdist_v2(v2f px, v2f py, v2f pz,
                                             v2f lx, v2f ly, v2f lz) {
#pragma clang fp contract(off)
  v2f dx = px - lx;
  v2f dy = py - ly;
  v2f dz = pz - lz;
  v2f xx = dx * dx;
  v2f yy = dy * dy;
  v2f zz = dz * dz;
  return (xx + yy) + zz;
}

// (x*x + y*y) + z*z, NO contraction (np.sum forward order, n=3).
__device__ __forceinline__ float sumsq3(float x, float y, float z) {
#pragma clang fp contract(off)
  return (x * x + y * y) + z * z;
}

// Ball-query expanded form: (sc + sx) - 2*dot, NO contraction on the adds.
__device__ __forceinline__ float bq_d2(float sc, float sx,
                                       float cx, float cy, float cz,
                                       float x, float y, float z) {
#pragma clang fp contract(off)
  float dt = fmaf(cz, z, fmaf(cy, y, cx * x));
  return (sc + sx) - 2.0f * dt;
}

// u64 max with the partner lane's key fetched via DPP (VALU pipe, no LDS).
template <int CTRL>
__device__ __forceinline__ unsigned long long kmax_dpp(unsigned long long k) {
  int lo = (int)(unsigned int)(k & 0xFFFFFFFFull);
  int hi = (int)(unsigned int)(k >> 32);
  int slo = __builtin_amdgcn_update_dpp(lo, lo, CTRL, 0xF, 0xF, false);
  int shi = __builtin_amdgcn_update_dpp(hi, hi, CTRL, 0xF, 0xF, false);
  unsigned long long sk =
      ((unsigned long long)(unsigned int)shi << 32) | (unsigned int)slo;
  return sk > k ? sk : k;
}

// ---------------------------------------------------------------------------
// Kernel 0: weight transpose + ring reset (stream-ordered; re-zeroes the ring
// on every graph replay BEFORE the mega kernel runs).
// ---------------------------------------------------------------------------
__global__ __launch_bounds__(256) void init_kernel(
    const float* __restrict__ w1, const float* __restrict__ w2,
    const float* __restrict__ w3, float* __restrict__ wT,
    unsigned* __restrict__ ring)
{
  const int t = threadIdx.x;
  int idx = blockIdx.x * 256 + t;
  if (idx < RING_U32) ring[idx] = 0u;   // bit31 clear = empty
  if (idx < 67*64) {
    int c = idx >> 6, o = idx & 63;
    wT[idx] = w1[o*67 + c];
  } else if (idx < 67*64 + 64*64) {
    int r = idx - 67*64; int c = r >> 6, o = r & 63;
    wT[idx] = w2[o*64 + c];
  } else if (idx < 67*64 + 64*64 + 64*128) {
    int r = idx - (67*64 + 64*64); int c = r >> 7, o = r & 127;
    wT[idx] = w3[o*64 + c];
  }
}

// ---------------------------------------------------------------------------
// Mega kernel. Blocks 0..7: FPS producers. Blocks 8..8199: one-shot sa
// consumers, two 128-thread halves per block, cid = 2*(blk-8)+half, s-major
// interleave (b=cid&7, s=cid>>3).
// LDS union (26640 floats = 106,560 B -> 1 block/CU; FPS CUs exclusive):
//   FPS: sX[0..8191] sY[8192..16383] sZ[16384..24575]
//        hist(int)[24576..26623]  redk(u64[2][4])[26624..26639]
//   SA : in_/y_ half0 [0..4351], half1 [4352..8703]; gidx [8704..8767];
//        csl [8768..8775]
// ---------------------------------------------------------------------------
__global__ __launch_bounds__(256, 1) void mega_kernel(
    const float* __restrict__ xyzs, const float* __restrict__ feats,
    float* centers, const float* __restrict__ wT, unsigned* ring,
    const float* __restrict__ b1, const float* __restrict__ g1, const float* __restrict__ bt1,
    const float* __restrict__ m1, const float* __restrict__ v1,
    const float* __restrict__ b2, const float* __restrict__ g2, const float* __restrict__ bt2,
    const float* __restrict__ m2, const float* __restrict__ v2,
    const float* __restrict__ b3, const float* __restrict__ g3, const float* __restrict__ bt3,
    const float* __restrict__ m3, const float* __restrict__ v3,
    float* out_feats)
{
  __shared__ __align__(16) float smem[26640];

  if (blockIdx.x < NB) {
    // =============================== FPS =================================
    __builtin_amdgcn_s_setprio(3);
    const int b = blockIdx.x;
    const int t = threadIdx.x;
    const float* xb = xyzs + (size_t)b * NPTS * 3;
    unsigned* ring_b = ring + b * SCTR;
    float* cb_ = centers + (size_t)b * SCTR * 3;

    float* sX = smem;
    float* sY = smem + 8192;
    float* sZ = smem + 16384;
    int*  hist = (int*)(smem + 24576);                       // [2048]
    unsigned long long* redk = (unsigned long long*)(smem + 26624);  // [2][4]

    for (int i = t; i < NPTS; i += 256) {
      sX[i] = xb[3*i+0];
      sY[i] = xb[3*i+1];
      sZ[i] = xb[3*i+2];
    }
    if (t == 0) hist[0] = 0;   // reference: first center is index 0
    __syncthreads();

    const int t4 = 4 * t;

    // 32 loop-invariant points (8 quads strided 1024) in NAMED registers.
    const float4 xA = *(const float4*)(sX + 0    + t4);
    const float4 yA = *(const float4*)(sY + 0    + t4);
    const float4 zA = *(const float4*)(sZ + 0    + t4);
    const float4 xB = *(const float4*)(sX + 1024 + t4);
    const float4 yB = *(const float4*)(sY + 1024 + t4);
    const float4 zB = *(const float4*)(sZ + 1024 + t4);
    const float4 xC = *(const float4*)(sX + 2048 + t4);
    const float4 yC = *(const float4*)(sY + 2048 + t4);
    const float4 zC = *(const float4*)(sZ + 2048 + t4);
    const float4 xD = *(const float4*)(sX + 3072 + t4);
    const float4 yD = *(const float4*)(sY + 3072 + t4);
    const float4 zD = *(const float4*)(sZ + 3072 + t4);
    const float4 xE = *(const float4*)(sX + 4096 + t4);
    const float4 yE = *(const float4*)(sY + 4096 + t4);
    const float4 zE = *(const float4*)(sZ + 4096 + t4);
    const float4 xF = *(const float4*)(sX + 5120 + t4);
    const float4 yF = *(const float4*)(sY + 5120 + t4);
    const float4 zF = *(const float4*)(sZ + 5120 + t4);
    const float4 xG = *(const float4*)(sX + 6144 + t4);
    const float4 yG = *(const float4*)(sY + 6144 + t4);
    const float4 zG = *(const float4*)(sZ + 6144 + t4);
    const float4 xH = *(const float4*)(sX + 7168 + t4);
    const float4 yH = *(const float4*)(sY + 7168 + t4);
    const float4 zH = *(const float4*)(sZ + 7168 + t4);

    float4 mA = make_float4(1e10f,1e10f,1e10f,1e10f);
    float4 mB = mA, mC = mA, mD = mA, mE = mA, mF = mA, mG = mA, mH = mA;

    float lx = sX[0], ly = sY[0], lz = sZ[0];
    int stash = 0;                 // lane t<16: winner index for s%16 == t

// R21: min-updates verbatim; per-quad fmax tree (index-free, depth 2);
// quad-id chain link (strict >). Distance source form UNCHANGED.
#define FPS_QUAD(QX, QY, QZ, MV, QID, BV, BQ)                                   \
  do {                                                                          \
    v2f d;                                                                      \
    d = fps_sqdist_v2((v2f){QX.x,QX.y}, (v2f){QY.x,QY.y}, (v2f){QZ.x,QZ.y},     \
                      lxv, lyv, lzv);                                           \
    MV.x = fminf(MV.x, d.x);                                                    \
    MV.y = fminf(MV.y, d.y);                                                    \
    d = fps_sqdist_v2((v2f){QX.z,QX.w}, (v2f){QY.z,QY.w}, (v2f){QZ.z,QZ.w},     \
                      lxv, lyv, lzv);                                           \
    MV.z = fminf(MV.z, d.x);                                                    \
    MV.w = fminf(MV.w, d.y);                                                    \
    float qm_ = fmaxf(fmaxf(MV.x, MV.y), fmaxf(MV.z, MV.w));                    \
    if (qm_ > BV) { BV = qm_; BQ = (QID); }                                     \
  } while (0)

    for (int s = 1; s < SCTR; ++s) {
      float bv0 = -1.0f, bv1 = -1.0f; int bq0 = 0, bq1 = 4;
      {
        v2f lxv = {lx, lx}, lyv = {ly, ly}, lzv = {lz, lz};
        FPS_QUAD(xA, yA, zA, mA, 0, bv0, bq0);
        FPS_QUAD(xB, yB, zB, mB, 1, bv0, bq0);
        FPS_QUAD(xC, yC, zC, mC, 2, bv0, bq0);
        FPS_QUAD(xD, yD, zD, mD, 3, bv0, bq0);
        FPS_QUAD(xE, yE, zE, mE, 4, bv1, bq1);
        FPS_QUAD(xF, yF, zF, mF, 5, bv1, bq1);
        FPS_QUAD(xG, yG, zG, mG, 6, bv1, bq1);
        FPS_QUAD(xH, yH, zH, mH, 7, bv1, bq1);
      }
      float bv = bv0; int bq = bq0;
      if (bv1 > bv0) { bv = bv1; bq = bq1; }   // chain1 quads all higher-index

      // post-chain reconstruction: select winning quad's MV (depth-3 binary
      // tree on bq bits, named registers only — R5 lesson), then first
      // element equal to bv (fmaxf returns an operand bit-exactly; all
      // minds >= +0 so == is well-defined; first-match = reference order).
      float4 s0_ = (bq & 1) ? mB : mA;
      float4 s1_ = (bq & 1) ? mD : mC;
      float4 s2_ = (bq & 1) ? mF : mE;
      float4 s3_ = (bq & 1) ? mH : mG;
      float4 p0_ = (bq & 2) ? s1_ : s0_;
      float4 p1_ = (bq & 2) ? s3_ : s2_;
      float4 mq_ = (bq & 4) ? p1_ : p0_;
      int j_ = (bv == mq_.x) ? 0 : ((bv == mq_.y) ? 1 : ((bv == mq_.z) ? 2 : 3));
      int bg = (bq << 10) + t4 + j_;

      unsigned long long key =
          ((unsigned long long)__float_as_uint(bv) << 13) |
          (unsigned long long)(8191 - bg);

      key = kmax_dpp<0x111>(key);   // row_shr:1
      key = kmax_dpp<0x112>(key);   // row_shr:2
      key = kmax_dpp<0x114>(key);   // row_shr:4
      key = kmax_dpp<0x118>(key);   // row_shr:8
      key = kmax_dpp<0x142>(key);   // row_bcast:15
      key = kmax_dpp<0x143>(key);   // row_bcast:31

      int pb = s & 1;
      if ((t & 63) == 63) redk[pb*4 + (t >> 6)] = key;
      __syncthreads();

      unsigned long long k4 = redk[pb*4 + (t & 3)];
      k4 = kmax_dpp<0xB1>(k4);      // quad_perm [1,0,3,2]
      k4 = kmax_dpp<0x4E>(k4);      // quad_perm [2,3,0,1]

      int i0 = 8191 - (int)(k4 & 0x1FFFull);
      lx = sX[i0]; ly = sY[i0]; lz = sZ[i0];
      if (t == 0) hist[s] = i0;

      // per-lane stash: lane (s&15) of wave 0 keeps this winner's index
      if (t < 16 && (s & 15) == t) stash = i0;
      // publish 16 self-validating index mailboxes every 16 iters (RELAXED 4B
      // atomics; ack latency hides under the next iteration's distance block).
      if ((s & 15) == 15 && t < 16) {
        __hip_atomic_store(ring_b + (s - 15) + t,
                           0x80000000u | (unsigned)stash,
                           __ATOMIC_RELAXED, __HIP_MEMORY_SCOPE_AGENT);
      }
    }
#undef FPS_QUAD

    // epilogue: write centers to d_out (read by the harness only — consumers
    // use the ring + xyzs). Kernel completion gives visibility.
    __syncthreads();
    for (int ss = t; ss < SCTR; ss += 256) {
      int i = hist[ss];
      float* o = cb_ + 3 * ss;
      o[0] = sX[i]; o[1] = sY[i]; o[2] = sZ[i];
    }
    return;
  }

  // ================================ SA ===================================
  constexpr float R2 = (float)(0.2 * 0.2);
  const int t    = threadIdx.x;
  const int jb   = blockIdx.x - NB;
  const int half = t >> 7;
  const int ht   = t & 127;
  const int w    = ht >> 6;        // wave id within half
  const int lane = ht & 63;
  const int cid  = 2 * jb + half;
  const int b    = cid & 7;
  const int s    = cid >> 3;
  const int bid  = b * SCTR + s;
  const float* xb = xyzs + (size_t)b * NPTS * 3;

  float* in_  = smem + half * 4352;          // [k][c] stride 68, col 67 zero pad
  float* y_   = in_ + 2176;                  // [k][c] stride 68
  int*   gidx = (int*)(smem + 8704) + half * KNN;
  float* csl  = smem + 8768 + half * 4;

  // ---- wait for our center's index mailbox; coords from immutable input ----
  if (ht == 0) {
    int i0 = 0;
    if (s > 0) {
      const unsigned* rp = ring + b * SCTR + s;
      unsigned v;
      while (!((v = __hip_atomic_load(rp, __ATOMIC_RELAXED,
                                      __HIP_MEMORY_SCOPE_AGENT)) & 0x80000000u))
        __builtin_amdgcn_s_sleep(32);
      i0 = (int)(v & 0x1FFFu);
    }
    const float* cg = xb + 3 * i0;           // input data: always coherent
    csl[0] = cg[0]; csl[1] = cg[1]; csl[2] = cg[2];
  }
  __syncthreads();
  const float cx = csl[0], cy = csl[1], cz = csl[2];
  const float sc = sumsq3(cx, cy, cz);

  // ---- ball query (both waves of the half identical; dup writes benign) ----
  int cnt = 0;
  for (int base = 0; base < NPTS && cnt < KNN; base += 64) {
    int n = base + lane;
    float x = xb[n*3+0], y = xb[n*3+1], z = xb[n*3+2];
    float sx = sumsq3(x, y, z);
    float d2 = bq_d2(sc, sx, cx, cy, cz, x, y, z);
    bool within = (d2 <= R2);
    unsigned long long mk = __ballot(within);
    int rank = __popcll(mk & ((1ull << lane) - 1ull));
    int slot = cnt + rank;
    if (within && slot < KNN) gidx[slot] = n;
    cnt += (int)__popcll(mk);
  }
  if (cnt > KNN) cnt = KNN;
  __syncthreads();

  // ---- gather: in_[k][0..2]=xyz-c, [3..66]=feats, [67]=0 pad ----
#pragma unroll 4
  for (int k2 = 0; k2 < 16; ++k2) {
    int k = 2*k2 + w;
    int gk = (k < cnt) ? gidx[k] : -1;
    float fv = 0.f, xv = 0.f;
    if (gk >= 0) {
      fv = feats[((size_t)b * NPTS + gk) * NF + lane];
      if (lane < 3) xv = xb[gk*3 + lane] - csl[lane];  // exact single op
    }
    in_[k*68 + 3 + lane] = fv;
    if (lane < 3) in_[k*68 + lane] = xv;
    if (lane == 3) in_[k*68 + 67] = 0.f;
  }
  __syncthreads();

  const int g  = lane >> 3;        // k-group: k = 4g..4g+3
  const int h  = lane & 7;         // o-subgroup
  const int ob = w*32 + 4*h;       // wave's o-base for L1/L2
  const float* w1T = wT;                  // [67][64]
  const float* w2T = wT + 67*64;          // [64][64]
  const float* w3T = wT + 67*64 + 64*64;  // [64][128]

// One c-column: 16 fmas, a-scalars from the chunk's float4s.
#define FMA_COL(AS0, AS1, AS2, AS3, WV)                                      \
  do {                                                                       \
    acc[0][0]=fmaf(AS0, WV.x, acc[0][0]); acc[0][1]=fmaf(AS0, WV.y, acc[0][1]); \
    acc[0][2]=fmaf(AS0, WV.z, acc[0][2]); acc[0][3]=fmaf(AS0, WV.w, acc[0][3]); \
    acc[1][0]=fmaf(AS1, WV.x, acc[1][0]); acc[1][1]=fmaf(AS1, WV.y, acc[1][1]); \
    acc[1][2]=fmaf(AS1, WV.z, acc[1][2]); acc[1][3]=fmaf(AS1, WV.w, acc[1][3]); \
    acc[2][0]=fmaf(AS2, WV.x, acc[2][0]); acc[2][1]=fmaf(AS2, WV.y, acc[2][1]); \
    acc[2][2]=fmaf(AS2, WV.z, acc[2][2]); acc[2][3]=fmaf(AS2, WV.w, acc[2][3]); \
    acc[3][0]=fmaf(AS3, WV.x, acc[3][0]); acc[3][1]=fmaf(AS3, WV.y, acc[3][1]); \
    acc[3][2]=fmaf(AS3, WV.z, acc[3][2]); acc[3][3]=fmaf(AS3, WV.w, acc[3][3]); \
  } while (0)

// One 4-c chunk: 4 ds_read_b128 (a by k), 4 global float4 (w rows), 64 fmas.
#define MLP_CHUNK(SRC, WBASE, WSTRIDE, WOFF)                                 \
  do {                                                                       \
    float4 a0 = *(const float4*)((SRC) + (4*g+0)*68 + c0);                   \
    float4 a1 = *(const float4*)((SRC) + (4*g+1)*68 + c0);                   \
    float4 a2 = *(const float4*)((SRC) + (4*g+2)*68 + c0);                   \
    float4 a3 = *(const float4*)((SRC) + (4*g+3)*68 + c0);                   \
    float4 wv0 = *(const float4*)(WBASE + (c0+0)*(WSTRIDE) + (WOFF));        \
    float4 wv1 = *(const float4*)(WBASE + (c0+1)*(WSTRIDE) + (WOFF));        \
    float4 wv2 = *(const float4*)(WBASE + (c0+2)*(WSTRIDE) + (WOFF));        \
    float4 wv3 = *(const float4*)(WBASE + (c0+3)*(WSTRIDE) + (WOFF));        \
    FMA_COL(a0.x, a1.x, a2.x, a3.x, wv0);                                    \
    FMA_COL(a0.y, a1.y, a2.y, a3.y, wv1);                                    \
    FMA_COL(a0.z, a1.z, a2.z, a3.z, wv2);                                    \
    FMA_COL(a0.w, a1.w, a2.w, a3.w, wv3);                                    \
  } while (0)

  // ---- Layer 1: 67 -> 64 (K padded to 68; col67=0 x w2T-row0 = exact no-op) ----
  {
    float acc[4][4];
#pragma unroll
    for (int i=0;i<4;++i)
#pragma unroll
      for (int j=0;j<4;++j) acc[i][j]=0.f;
#pragma unroll 2
    for (int c0 = 0; c0 < 68; c0 += 4) {
      MLP_CHUNK(in_, w1T, 64, ob);
    }
    float scl[4], shf[4];
#pragma unroll
    for (int j=0;j<4;++j) {
      int o = ob + j;
      float r = g1[o] * rsqrtf(v1[o] + 1e-5f);
      scl[j] = r;
      shf[j] = (b1[o] - m1[o]) * r + bt1[o];
    }
#pragma unroll
    for (int i=0;i<4;++i) {
      float4 out;
      out.x = fmaxf(fmaf(acc[i][0], scl[0], shf[0]), 0.f);
      out.y = fmaxf(fmaf(acc[i][1], scl[1], shf[1]), 0.f);
      out.z = fmaxf(fmaf(acc[i][2], scl[2], shf[2]), 0.f);
      out.w = fmaxf(fmaf(acc[i][3], scl[3], shf[3]), 0.f);
      *(float4*)(y_ + (4*g+i)*68 + ob) = out;   // ds_write_b128
    }
  }
  __syncthreads();

  // ---- Layer 2: 64 -> 64 (reads y_, writes in_ o-half) ----
  {
    float acc[4][4];
#pragma unroll
    for (int i=0;i<4;++i)
#pragma unroll
      for (int j=0;j<4;++j) acc[i][j]=0.f;
#pragma unroll 2
    for (int c0 = 0; c0 < 64; c0 += 4) {
      MLP_CHUNK(y_, w2T, 64, ob);
    }
    float scl[4], shf[4];
#pragma unroll
    for (int j=0;j<4;++j) {
      int o = ob + j;
      float r = g2[o] * rsqrtf(v2[o] + 1e-5f);
      scl[j] = r;
      shf[j] = (b2[o] - m2[o]) * r + bt2[o];
    }
    __syncthreads();  // all y_ reads done before in_ overwrite (cross-wave)
#pragma unroll
    for (int i=0;i<4;++i) {
      float4 out;
      out.x = fmaxf(fmaf(acc[i][0], scl[0], shf[0]), 0.f);
      out.y = fmaxf(fmaf(acc[i][1], scl[1], shf[1]), 0.f);
      out.z = fmaxf(fmaf(acc[i][2], scl[2], shf[2]), 0.f);
      out.w = fmaxf(fmaf(acc[i][3], scl[3], shf[3]), 0.f);
      *(float4*)(in_ + (4*g+i)*68 + ob) = out;   // ds_write_b128
    }
  }
  __syncthreads();

  // ---- Layer 3: 64 -> 128; wave w owns o in [w*64, w*64+64) via 2 passes ----
  for (int p = 0; p < 2; ++p) {
    const int o3 = w*64 + p*32 + 4*h;
    float acc[4][4];
#pragma unroll
    for (int i=0;i<4;++i)
#pragma unroll
      for (int j=0;j<4;++j) acc[i][j]=0.f;
#pragma unroll 2
    for (int c0 = 0; c0 < 64; c0 += 4) {
      MLP_CHUNK(in_, w3T, 128, o3);
    }
    float scl[4], shf[4];
#pragma unroll
    for (int j=0;j<4;++j) {
      int o = o3 + j;
      float r = g3[o] * rsqrtf(v3[o] + 1e-5f);
      scl[j] = r;
      shf[j] = (b3[o] - m3[o]) * r + bt3[o];
    }
    float vm[4];
#pragma unroll
    for (int j=0;j<4;++j) {
      float q0 = fmaxf(fmaf(acc[0][j], scl[j], shf[j]), 0.f);
      float q1 = fmaxf(fmaf(acc[1][j], scl[j], shf[j]), 0.f);
      float q2 = fmaxf(fmaf(acc[2][j], scl[j], shf[j]), 0.f);
      float q3 = fmaxf(fmaf(acc[3][j], scl[j], shf[j]), 0.f);
      vm[j] = fmaxf(fmaxf(q0,q1), fmaxf(q2,q3));
    }
#pragma unroll
    for (int mk = 8; mk < 64; mk <<= 1) {
#pragma unroll
      for (int j=0;j<4;++j) vm[j] = fmaxf(vm[j], __shfl_xor(vm[j], mk));
    }
    if (g == 0) {
      float* dst = out_feats + (size_t)bid*128 + o3;
      *(float4*)dst = make_float4(vm[0], vm[1], vm[2], vm[3]);
    }
  }
#undef MLP_CHUNK
#undef FMA_COL
}

// ---------------------------------------------------------------------------
extern "C" void kernel_launch(void* const* d_in, const int* in_sizes, int n_in,
                              void* d_out, int out_size, void* d_ws, size_t ws_size,
                              hipStream_t stream) {
  const float* xyzs  = (const float*)d_in[0];
  const float* feats = (const float*)d_in[1];
  const float* w1  = (const float*)d_in[2];
  const float* b1  = (const float*)d_in[3];
  const float* g1  = (const float*)d_in[4];
  const float* bt1 = (const float*)d_in[5];
  const float* m1  = (const float*)d_in[6];
  const float* v1  = (const float*)d_in[7];
  const float* w2  = (const float*)d_in[8];
  const float* b2  = (const float*)d_in[9];
  const float* g2  = (const float*)d_in[10];
  const float* bt2 = (const float*)d_in[11];
  const float* m2  = (const float*)d_in[12];
  const float* v2  = (const float*)d_in[13];
  const float* w3  = (const float*)d_in[14];
  const float* b3  = (const float*)d_in[15];
  const float* g3  = (const float*)d_in[16];
  const float* bt3 = (const float*)d_in[17];
  const float* m3  = (const float*)d_in[18];
  const float* v3  = (const float*)d_in[19];

  float* out       = (float*)d_out;
  float* centers   = out;                          // [8][2048][3]
  float* out_feats = out + (size_t)NB * SCTR * 3;  // [8][2048][128]
  float* wT        = (float*)d_ws;                 // 16576 floats
  unsigned* ring   = (unsigned*)((float*)d_ws + WT_FLOATS);  // [8][2048] u32

  // Kernel 0: transpose weights + zero ring (stream-ordered).
  hipLaunchKernelGGL(init_kernel, dim3(65), dim3(256), 0, stream,
                     w1, w2, w3, wT, ring);
  // Mega kernel: 8 FPS producer blocks (first!) + 8192 one-shot sa consumers.
  hipLaunchKernelGGL(mega_kernel, dim3(NB + NB * SCTR / 2), dim3(256), 0, stream,
                     xyzs, feats, centers, wT, ring,
                     b1, g1, bt1, m1, v1,
                     b2, g2, bt2, m2, v2,
                     b3, g3, bt3, m3, v3,
                     out_feats);
}